// Round 4
// baseline (4534.120 us; speedup 1.0000x reference)
//
#include <hip/hip_runtime.h>

// ---------------------------------------------------------------------------
// PointNet++ (SSG) forward on MI355X.
// B=4, N=4096. sa1: S1=2048 r=0.2 K=64, MLP 6-64-64-128.
//              sa2: S2=512  r=0.4 K=64, MLP 131-128-128-256.
//              sa3: MLP 259-256-512-1024 + global max. fc: 1024->256.
// All discrete decisions (FPS argmax, radius membership, top-64 rank) are
// computed with bitwise-exact f32 ops matching the reference association
// order. FPS distance math uses packed-f32 (v_pk_*) vector ops under
// fp contract(off): two IEEE-RN f32 ops per instruction, bitwise identical
// to scalar. FPS argmax key = (f32bits<<32 | ~idx): for non-negative f32,
// uint compare == float compare, and ~idx gives smaller-index-wins on ties --
// exactly jnp.argmax semantics.
// ---------------------------------------------------------------------------

#define DEVFN __device__ __forceinline__

typedef float v2f __attribute__((ext_vector_type(2)));

DEVFN float d2_exact(float ax, float ay, float az, float bx, float by, float bz) {
    float dx = __fsub_rn(ax, bx);
    float dy = __fsub_rn(ay, by);
    float dz = __fsub_rn(az, bz);
    return __fadd_rn(__fadd_rn(__fmul_rn(dx, dx), __fmul_rn(dy, dy)), __fmul_rn(dz, dz));
}

DEVFN unsigned long long u64max(unsigned long long a, unsigned long long b) {
    return a > b ? a : b;
}

// DPP rotate-right by R within each 16-lane row (all lanes valid -> no
// bound_ctrl concerns). Applied to a u64 as two 32-bit halves.
template <int R>
DEVFN unsigned long long dpp_ror16_u64(unsigned long long x) {
    int lo = (int)(unsigned)(x & 0xFFFFFFFFull);
    int hi = (int)(unsigned)(x >> 32);
    lo = __builtin_amdgcn_update_dpp(lo, lo, 0x120 | R, 0xF, 0xF, false);
    hi = __builtin_amdgcn_update_dpp(hi, hi, 0x120 | R, 0xF, 0xF, false);
    return ((unsigned long long)(unsigned)hi << 32) | (unsigned)lo;
}

// readlane both halves of a u64 from a fixed lane -> wave-uniform value
DEVFN unsigned long long rl_u64(unsigned long long x, int lane) {
    unsigned l = (unsigned)__builtin_amdgcn_readlane((int)(unsigned)(x & 0xFFFFFFFFull), lane);
    unsigned h = (unsigned)__builtin_amdgcn_readlane((int)(unsigned)(x >> 32), lane);
    return ((unsigned long long)h << 32) | l;
}

// ---------------------------------------------------------------------------
// FPS (both stages fused; one 512-thread block per cloud).
// Per iteration: packed-f32 dist+min (PPT pts/thread, 2/inst), local f32
// argmax tree with index tracking, single u64 key build, 4x DPP row_ror
// reduce, readlane cross-row combine -> ONE winner key per wave -> LDS
// (parity double-buffered), ONE barrier, all threads combine 8 keys.
// ---------------------------------------------------------------------------
template <int N, int S, int NT>
DEVFN void run_fps(const float* sx, const float* sy, const float* sz,
                   unsigned long long* sPack,  // [2][NT/64]
                   int* selLds) {
#pragma clang fp contract(off)
    constexpr int PPT = N / NT;
    constexpr int PH = PPT / 2;
    constexpr int NW = NT / 64;
    const int tid = threadIdx.x;
    v2f px2[PH], py2[PH], pz2[PH], md2[PH];
#pragma unroll
    for (int j = 0; j < PH; ++j) {
        px2[j] = *(const v2f*)(sx + tid * PPT + 2 * j);
        py2[j] = *(const v2f*)(sy + tid * PPT + 2 * j);
        pz2[j] = *(const v2f*)(sz + tid * PPT + 2 * j);
        md2[j].x = __builtin_inff();  // first pass (cur=0) -> dist-to-point-0
        md2[j].y = __builtin_inff();
    }
    if (tid == 0) selLds[0] = 0;
    const unsigned lob = 0xFFFFFFFFu - (unsigned)(tid * PPT);  // ~(tid*PPT)
    float ax = sx[0], ay = sy[0], az = sz[0];
    for (int s = 1; s < S; ++s) {
        v2f axv; axv.x = ax; axv.y = ax;
        v2f ayv; ayv.x = ay; ayv.y = ay;
        v2f azv; azv.x = az; azv.y = az;
        float mm[PPT]; int li[PPT];
#pragma unroll
        for (int j = 0; j < PH; ++j) {
            // packed f32: two points per instruction, IEEE RN, no contraction
            v2f dx = px2[j] - axv;
            v2f dy = py2[j] - ayv;
            v2f dz = pz2[j] - azv;
            v2f xx = dx * dx;
            v2f yy = dy * dy;
            v2f zz = dz * dz;
            v2f d = (xx + yy) + zz;   // ((dx^2+dy^2)+dz^2), reference order
            float m0 = fminf(md2[j].x, d.x);
            float m1 = fminf(md2[j].y, d.y);
            md2[j].x = m0; md2[j].y = m1;
            mm[2 * j] = m0; mm[2 * j + 1] = m1;
            li[2 * j] = 2 * j; li[2 * j + 1] = 2 * j + 1;
        }
        // local argmax tree: strict > keeps lower local index on ties,
        // which matches the u64 (~idx) ordering within a lane.
#pragma unroll
        for (int w = PPT / 2; w >= 1; w >>= 1)
#pragma unroll
            for (int i = 0; i < w; ++i) {
                bool cgt = mm[i + w] > mm[i];
                mm[i] = cgt ? mm[i + w] : mm[i];
                li[i] = cgt ? li[i + w] : li[i];
            }
        unsigned long long k0 =
            ((unsigned long long)__float_as_uint(mm[0]) << 32) |
            (unsigned long long)(lob - (unsigned)li[0]);

        k0 = u64max(k0, dpp_ror16_u64<8>(k0));
        k0 = u64max(k0, dpp_ror16_u64<4>(k0));
        k0 = u64max(k0, dpp_ror16_u64<2>(k0));
        k0 = u64max(k0, dpp_ror16_u64<1>(k0));  // each 16-lane row: row max

        // cross-row combine via readlane (wave-uniform result)
        unsigned long long wmax = u64max(u64max(rl_u64(k0, 0), rl_u64(k0, 16)),
                                         u64max(rl_u64(k0, 32), rl_u64(k0, 48)));

        unsigned long long* sp = sPack + (s & 1) * NW;
        if ((tid & 63) == 0) sp[tid >> 6] = wmax;
        __syncthreads();

        const ulonglong2* sp2 = (const ulonglong2*)sp;  // NW=8 -> 4 x b128
        ulonglong2 q0 = sp2[0], q1 = sp2[1], q2 = sp2[2], q3 = sp2[3];
        unsigned long long m01 = u64max(u64max(q0.x, q0.y), u64max(q1.x, q1.y));
        unsigned long long m23 = u64max(u64max(q2.x, q2.y), u64max(q3.x, q3.y));
        unsigned long long win = u64max(m01, m23);

        int cur = (int)(0xFFFFFFFFu - (unsigned)(win & 0xFFFFFFFFull));
        ax = sx[cur]; ay = sy[cur]; az = sz[cur];  // uniform LDS broadcast
        if (tid == 0) selLds[s] = cur;
        // no second barrier: next iteration writes the other parity slot set,
        // and the following barrier orders reuse.
    }
}

__global__ __launch_bounds__(512) void fps_kernel(const float* __restrict__ data,
                                                  float* __restrict__ pos1,
                                                  float* __restrict__ pos2) {
    __shared__ __align__(16) float sx[4096];
    __shared__ __align__(16) float sy[4096];
    __shared__ __align__(16) float sz[4096];
    __shared__ __align__(16) unsigned long long sPack[16];  // [2][8]
    __shared__ int sSel1[2048];
    __shared__ int sSel2[512];

    const int b = blockIdx.x, tid = threadIdx.x;
    const float* p = data + (size_t)b * 4096 * 3;
    for (int i = tid; i < 4096; i += 512) {
        sx[i] = p[i * 3 + 0]; sy[i] = p[i * 3 + 1]; sz[i] = p[i * 3 + 2];
    }
    __syncthreads();

    run_fps<4096, 2048, 512>(sx, sy, sz, sPack, sSel1);
    __syncthreads();

    // gather pos1 and compact LDS SoA to the first 2048 slots (stage-2 input)
    float gx[4], gy[4], gz[4];
#pragma unroll
    for (int i = 0; i < 4; ++i) {
        int si = sSel1[tid * 4 + i];
        gx[i] = sx[si]; gy[i] = sy[si]; gz[i] = sz[si];
    }
    __syncthreads();
    float* p1 = pos1 + (size_t)b * 2048 * 3;
#pragma unroll
    for (int i = 0; i < 4; ++i) {
        int o = tid * 4 + i;
        sx[o] = gx[i]; sy[o] = gy[i]; sz[o] = gz[i];
        p1[o * 3 + 0] = gx[i]; p1[o * 3 + 1] = gy[i]; p1[o * 3 + 2] = gz[i];
    }
    __syncthreads();

    run_fps<2048, 512, 512>(sx, sy, sz, sPack, sSel2);
    __syncthreads();

    float* p2 = pos2 + (size_t)b * 512 * 3;
    {
        int si = sSel2[tid];
        p2[tid * 3 + 0] = sx[si]; p2[tid * 3 + 1] = sy[si]; p2[tid * 3 + 2] = sz[si];
    }
}

// ---------------------------------------------------------------------------
// Radius neighbors, exact top-64 by (d2 asc, idx asc) -- one wave per center
// ---------------------------------------------------------------------------
template <int N, int CAP>
__global__ __launch_bounds__(256) void nbr_kernel(const float* __restrict__ pos,  // [B][N][3]
                                                  const float* __restrict__ ctr,  // [B*S][3]
                                                  const int S, const float rsq,
                                                  int* __restrict__ nbr,          // [B*S][64]
                                                  int* __restrict__ cnt) {
    __shared__ float sD[4][CAP];
    __shared__ int   sI[4][CAP];
    const int wid = threadIdx.x >> 6, lane = threadIdx.x & 63;
    const int c = blockIdx.x * 4 + wid;
    const int b = c / S;
    const float* p = pos + (size_t)b * N * 3;
    const float cx = ctr[(size_t)c * 3 + 0];
    const float cy = ctr[(size_t)c * 3 + 1];
    const float cz = ctr[(size_t)c * 3 + 2];

    int count = 0;  // wave-uniform
    for (int j = lane; j < N; j += 64) {
        float d = d2_exact(cx, cy, cz, p[j * 3 + 0], p[j * 3 + 1], p[j * 3 + 2]);
        bool pred = (d <= rsq);
        unsigned long long m = __ballot(pred);
        int wpos = count + __popcll(m & ((1ull << lane) - 1ull));
        if (pred && wpos < CAP) { sD[wid][wpos] = d; sI[wid][wpos] = j; }
        count += __popcll(m);
    }
    if (count > CAP) count = CAP;

    for (int t = lane; t < count; t += 64) {
        float d = sD[wid][t]; int id = sI[wid][t];
        int rank = 0;
        for (int j0 = 0; j0 < count; ++j0) {
            float dj = sD[wid][j0]; int ij = sI[wid][j0];
            rank += (dj < d || (dj == d && ij < id)) ? 1 : 0;
        }
        if (rank < 64) nbr[(size_t)c * 64 + rank] = id;
    }
    if (lane == 0) cnt[c] = count < 64 ? count : 64;
}

// ---------------------------------------------------------------------------
// Register-tile FMA helpers (A from LDS, W from LDS; float4 k-blocks)
// ---------------------------------------------------------------------------
DEVFN void tile44_fma(const float* __restrict__ aBase, int aStride,
                      const float* __restrict__ wBase, int wStride,
                      int nk4, float (&acc)[4][4]) {
    for (int k4 = 0; k4 < nk4; ++k4) {
        float a[4][4], w[4][4];
#pragma unroll
        for (int i = 0; i < 4; ++i) {
            float4 t = *(const float4*)(aBase + i * aStride + k4 * 4);
            a[i][0] = t.x; a[i][1] = t.y; a[i][2] = t.z; a[i][3] = t.w;
        }
#pragma unroll
        for (int kk = 0; kk < 4; ++kk) {
            float4 t = *(const float4*)(wBase + (k4 * 4 + kk) * wStride);
            w[kk][0] = t.x; w[kk][1] = t.y; w[kk][2] = t.z; w[kk][3] = t.w;
        }
#pragma unroll
        for (int kk = 0; kk < 4; ++kk)
#pragma unroll
            for (int i = 0; i < 4; ++i)
#pragma unroll
                for (int j = 0; j < 4; ++j)
                    acc[i][j] = fmaf(a[i][kk], w[kk][j], acc[i][j]);
    }
}

DEVFN void tile48_fma(const float* __restrict__ aBase, int aStride,
                      const float* __restrict__ wBase, int wStride,
                      int nk4, float (&acc)[4][8]) {
    for (int k4 = 0; k4 < nk4; ++k4) {
        float a[4][4];
#pragma unroll
        for (int i = 0; i < 4; ++i) {
            float4 t = *(const float4*)(aBase + i * aStride + k4 * 4);
            a[i][0] = t.x; a[i][1] = t.y; a[i][2] = t.z; a[i][3] = t.w;
        }
#pragma unroll
        for (int kk = 0; kk < 4; ++kk) {
            float4 t0 = *(const float4*)(wBase + (k4 * 4 + kk) * wStride);
            float4 t1 = *(const float4*)(wBase + (k4 * 4 + kk) * wStride + 4);
            float w_[8] = {t0.x, t0.y, t0.z, t0.w, t1.x, t1.y, t1.z, t1.w};
#pragma unroll
            for (int i = 0; i < 4; ++i)
#pragma unroll
                for (int j = 0; j < 8; ++j)
                    acc[i][j] = fmaf(a[i][kk], w_[j], acc[i][j]);
        }
    }
}

// ---------------------------------------------------------------------------
// sa1 MLP: feats[64][6] -> 64 -> 64 -> 128, masked max over rows. Block/center.
// ---------------------------------------------------------------------------
__global__ __launch_bounds__(256) void mlp1_kernel(
    const float* __restrict__ pos,   // [B][4096][3]
    const float* __restrict__ ctr,   // [8192][3]
    const int* __restrict__ nbr, const int* __restrict__ cnt,
    const float* __restrict__ w1, const float* __restrict__ b1,
    const float* __restrict__ w2, const float* __restrict__ b2,
    const float* __restrict__ w3, const float* __restrict__ b3,
    float* __restrict__ x1)          // [8192][128]
{
    __shared__ __align__(16) float smem[15424];
    float* sFeat = smem;            // [64][9]   (576)
    float* sW    = smem + 576;      // w2 [64][64]=4096 ; layer3: w3 [64][128]=8192 (spills over dead sH1)
    float* sH1   = smem + 4672;     // [64][68]  (4352)
    float* sH2   = smem + 9024;     // [64][68]  (4352)
    float* sRed  = smem + 13376;    // [16][128] (2048)

    const int tid = threadIdx.x;
    const int c = blockIdx.x;
    const int b = c >> 11;          // / 2048
    const int valid = cnt[c];

    if (tid < 64) {
        const int r = tid;
        float fx = 0.f, fy = 0.f, fz = 0.f, dx = 0.f, dy = 0.f, dz = 0.f;
        if (r < valid) {
            int j = nbr[(size_t)c * 64 + r];
            const float* pj = pos + ((size_t)b * 4096 + j) * 3;
            fx = pj[0]; fy = pj[1]; fz = pj[2];
            dx = fx - ctr[c * 3 + 0]; dy = fy - ctr[c * 3 + 1]; dz = fz - ctr[c * 3 + 2];
        }
        float* fr = sFeat + r * 9;
        fr[0] = fx; fr[1] = fy; fr[2] = fz; fr[3] = dx; fr[4] = dy; fr[5] = dz;
    }
    for (int l = tid; l < 4096; l += 256) sW[l] = w2[l];
    __syncthreads();

    // layer1: [64][6] @ [6][64] + b1, relu
    {
        const int r = tid & 63, c0 = (tid >> 6) * 16;
        float acc[16];
#pragma unroll
        for (int q = 0; q < 16; ++q) acc[q] = b1[c0 + q];
#pragma unroll
        for (int k = 0; k < 6; ++k) {
            float a = sFeat[r * 9 + k];
#pragma unroll
            for (int q = 0; q < 16; ++q) acc[q] = fmaf(a, w1[k * 64 + c0 + q], acc[q]);
        }
        float* hr = sH1 + r * 68 + c0;
#pragma unroll
        for (int q = 0; q < 16; ++q) hr[q] = fmaxf(acc[q], 0.f);
    }
    __syncthreads();

    // layer2: [64][64] @ [64][64] + b2, relu
    {
        const int r0 = (tid >> 4) * 4, c0 = (tid & 15) * 4;
        float acc[4][4];
#pragma unroll
        for (int i = 0; i < 4; ++i)
#pragma unroll
            for (int j = 0; j < 4; ++j) acc[i][j] = b2[c0 + j];
        tile44_fma(sH1 + r0 * 68, 68, sW + c0, 64, 16, acc);
#pragma unroll
        for (int i = 0; i < 4; ++i)
#pragma unroll
            for (int j = 0; j < 4; ++j)
                sH2[(r0 + i) * 68 + c0 + j] = fmaxf(acc[i][j], 0.f);
    }
    __syncthreads();

    // layer3: [64][64] @ [64][128], masked max over valid rows, + b3
    for (int l = tid; l < 8192; l += 256) sW[l] = w3[l];
    __syncthreads();
    {
        const int r0 = (tid >> 4) * 4, c0 = (tid & 15) * 8;
        float acc[4][8];
#pragma unroll
        for (int i = 0; i < 4; ++i)
#pragma unroll
            for (int j = 0; j < 8; ++j) acc[i][j] = 0.f;
        tile48_fma(sH2 + r0 * 68, 68, sW + c0, 128, 16, acc);
        float pm[8];
#pragma unroll
        for (int j = 0; j < 8; ++j) pm[j] = -__builtin_inff();
#pragma unroll
        for (int i = 0; i < 4; ++i)
            if (r0 + i < valid)
#pragma unroll
                for (int j = 0; j < 8; ++j) pm[j] = fmaxf(pm[j], acc[i][j]);
#pragma unroll
        for (int j = 0; j < 8; ++j) sRed[(tid >> 4) * 128 + c0 + j] = pm[j];
    }
    __syncthreads();
    if (tid < 128) {
        float m = -__builtin_inff();
#pragma unroll
        for (int g = 0; g < 16; ++g) m = fmaxf(m, sRed[g * 128 + tid]);
        x1[(size_t)c * 128 + tid] = m + b3[tid];
    }
}

// ---------------------------------------------------------------------------
// sa2 MLP: feats[64][131] -> 128 -> 128 -> 256, masked max. Block/center,
// two row-passes of 32 to fit LDS.
// ---------------------------------------------------------------------------
__global__ __launch_bounds__(256) void mlp2_kernel(
    const float* __restrict__ x1,    // [B*2048][128]
    const float* __restrict__ pos1,  // [B*2048][3]
    const float* __restrict__ ctr,   // [2048][3]
    const int* __restrict__ nbr, const int* __restrict__ cnt,
    const float* __restrict__ w1, const float* __restrict__ b1,
    const float* __restrict__ w2, const float* __restrict__ b2,
    const float* __restrict__ w3, const float* __restrict__ b3,
    float* __restrict__ x2)          // [2048][256]
{
    __shared__ __align__(16) float smem[14848];
    float* sF   = smem;              // [32][132] feats, then h2
    float* sH   = smem + 4224;       // [32][132] h1
    float* sWt  = smem + 8448;       // [32][128] staged W tile (l1/l2)
    float* sW3  = smem + 4224;       // [32][256] staged W3 tile (overlaps dead sH+sWt)
    float* sCM  = smem + 12544;      // [256] col max accumulator
    float* sRed = smem + 12800;      // [8][256]

    const int tid = threadIdx.x;
    const int c = blockIdx.x;
    const int b = c >> 9;            // / 512
    const int valid = cnt[c];
    const float cx = ctr[c * 3 + 0], cy = ctr[c * 3 + 1], cz = ctr[c * 3 + 2];

    sCM[tid] = -__builtin_inff();

    for (int pass = 0; pass < 2; ++pass) {
        const int rbase = pass * 32;
        // load feats rows [rbase, rbase+32)
        {
            const int r = tid >> 3, t8 = tid & 7;
            const int rr = rbase + r;
            float* fr = sF + r * 132;
            if (rr < valid) {
                int j = nbr[(size_t)c * 64 + rr];
                const float* xp = x1 + ((size_t)b * 2048 + j) * 128;
#pragma unroll
                for (int q = 0; q < 4; ++q) {
                    float4 v = *(const float4*)(xp + t8 * 16 + q * 4);
                    fr[t8 * 16 + q * 4 + 0] = v.x; fr[t8 * 16 + q * 4 + 1] = v.y;
                    fr[t8 * 16 + q * 4 + 2] = v.z; fr[t8 * 16 + q * 4 + 3] = v.w;
                }
                if (t8 == 0) {
                    const float* pj = pos1 + ((size_t)b * 2048 + j) * 3;
                    fr[128] = pj[0] - cx; fr[129] = pj[1] - cy; fr[130] = pj[2] - cz;
                    fr[131] = 0.f;
                }
            } else {
#pragma unroll
                for (int q = 0; q < 16; ++q) fr[t8 * 16 + q] = 0.f;
                if (t8 == 0) { fr[128] = 0.f; fr[129] = 0.f; fr[130] = 0.f; fr[131] = 0.f; }
            }
        }
        __syncthreads();

        // layer1: K=131 (padded 132), out sH[32][128], relu
        {
            const int r0 = ((tid >> 5) & 7) * 4, c0 = (tid & 31) * 4;
            float acc[4][4];
#pragma unroll
            for (int i = 0; i < 4; ++i)
#pragma unroll
                for (int j = 0; j < 4; ++j) acc[i][j] = b1[c0 + j];
            for (int kb = 0; kb < 132; kb += 32) {
                const int kt = (132 - kb) < 32 ? (132 - kb) : 32;  // 32,32,32,32,4
                for (int l = tid; l < kt * 128; l += 256) {
                    int k = l >> 7, cc = l & 127;
                    sWt[k * 128 + cc] = (kb + k < 131) ? w1[(size_t)(kb + k) * 128 + cc] : 0.f;
                }
                __syncthreads();
                tile44_fma(sF + r0 * 132 + kb, 132, sWt + c0, 128, kt / 4, acc);
                __syncthreads();
            }
#pragma unroll
            for (int i = 0; i < 4; ++i)
#pragma unroll
                for (int j = 0; j < 4; ++j)
                    sH[(r0 + i) * 132 + c0 + j] = fmaxf(acc[i][j], 0.f);
        }
        __syncthreads();

        // layer2: K=128, sH -> sF (h2), relu
        {
            const int r0 = ((tid >> 5) & 7) * 4, c0 = (tid & 31) * 4;
            float acc[4][4];
#pragma unroll
            for (int i = 0; i < 4; ++i)
#pragma unroll
                for (int j = 0; j < 4; ++j) acc[i][j] = b2[c0 + j];
            for (int kb = 0; kb < 128; kb += 32) {
                for (int l = tid; l < 32 * 128; l += 256) {
                    int k = l >> 7, cc = l & 127;
                    sWt[k * 128 + cc] = w2[(size_t)(kb + k) * 128 + cc];
                }
                __syncthreads();
                tile44_fma(sH + r0 * 132 + kb, 132, sWt + c0, 128, 8, acc);
                __syncthreads();
            }
#pragma unroll
            for (int i = 0; i < 4; ++i)
#pragma unroll
                for (int j = 0; j < 4; ++j)
                    sF[(r0 + i) * 132 + c0 + j] = fmaxf(acc[i][j], 0.f);
        }
        __syncthreads();

        // layer3: K=128, cols=256, masked col-max into sCM
        {
            const int r0 = ((tid >> 5) & 7) * 4, c0 = (tid & 31) * 8;
            float acc[4][8];
#pragma unroll
            for (int i = 0; i < 4; ++i)
#pragma unroll
                for (int j = 0; j < 8; ++j) acc[i][j] = 0.f;
            for (int kb = 0; kb < 128; kb += 32) {
                for (int l = tid; l < 32 * 256; l += 256) {
                    int k = l >> 8, cc = l & 255;
                    sW3[k * 256 + cc] = w3[(size_t)(kb + k) * 256 + cc];
                }
                __syncthreads();
                tile48_fma(sF + r0 * 132 + kb, 132, sW3 + c0, 256, 8, acc);
                __syncthreads();
            }
            float pm[8];
#pragma unroll
            for (int j = 0; j < 8; ++j) pm[j] = -__builtin_inff();
#pragma unroll
            for (int i = 0; i < 4; ++i)
                if (rbase + r0 + i < valid)
#pragma unroll
                    for (int j = 0; j < 8; ++j) pm[j] = fmaxf(pm[j], acc[i][j]);
#pragma unroll
            for (int j = 0; j < 8; ++j) sRed[((tid >> 5) & 7) * 256 + c0 + j] = pm[j];
        }
        __syncthreads();
        {
            float m = -__builtin_inff();
#pragma unroll
            for (int g = 0; g < 8; ++g) m = fmaxf(m, sRed[g * 256 + tid]);
            sCM[tid] = fmaxf(sCM[tid], m);
        }
        __syncthreads();
    }
    x2[(size_t)c * 256 + tid] = sCM[tid] + b3[tid];
}

// ---------------------------------------------------------------------------
// sa3: pack cat([x2,pos2]) -> 3 GEMMs -> max-pool -> fc
// ---------------------------------------------------------------------------
__global__ __launch_bounds__(64) void pack3_kernel(const float* __restrict__ x2,
                                                   const float* __restrict__ pos2,
                                                   float* __restrict__ xin) {
    const int row = blockIdx.x, tid = threadIdx.x;
    for (int cc = tid; cc < 259; cc += 64)
        xin[(size_t)row * 259 + cc] = (cc < 256) ? x2[(size_t)row * 256 + cc]
                                                 : pos2[row * 3 + (cc - 256)];
}

__global__ __launch_bounds__(256) void gemm_kernel(const float* __restrict__ A,
                                                   const float* __restrict__ W,
                                                   const float* __restrict__ bias,
                                                   float* __restrict__ C,
                                                   int M, int K, int Nc, int relu) {
    __shared__ __align__(16) float sA[64 * 36];
    __shared__ __align__(16) float sB[32 * 68];
    const int tid = threadIdx.x;
    const int row0 = blockIdx.y * 64, col0 = blockIdx.x * 64;
    const int r0 = (tid >> 4) * 4, c0 = (tid & 15) * 4;
    float acc[4][4];
#pragma unroll
    for (int i = 0; i < 4; ++i)
#pragma unroll
        for (int j = 0; j < 4; ++j) acc[i][j] = 0.f;

    for (int kb = 0; kb < K; kb += 32) {
        for (int l = tid; l < 64 * 32; l += 256) {
            int r = l >> 5, k = l & 31;
            sA[r * 36 + k] = (kb + k < K) ? A[(size_t)(row0 + r) * K + kb + k] : 0.f;
        }
        for (int l = tid; l < 32 * 64; l += 256) {
            int k = l >> 6, cc = l & 63;
            sB[k * 68 + cc] = (kb + k < K) ? W[(size_t)(kb + k) * Nc + col0 + cc] : 0.f;
        }
        __syncthreads();
        tile44_fma(sA + r0 * 36, 36, sB + c0, 68, 8, acc);
        __syncthreads();
    }
#pragma unroll
    for (int i = 0; i < 4; ++i)
#pragma unroll
        for (int j = 0; j < 4; ++j) {
            float v = acc[i][j] + bias[col0 + c0 + j];
            if (relu) v = fmaxf(v, 0.f);
            C[(size_t)(row0 + r0 + i) * Nc + col0 + c0 + j] = v;
        }
}

__global__ __launch_bounds__(256) void maxpool_kernel(const float* __restrict__ h,
                                                      float* __restrict__ g) {
    const int b = blockIdx.y, col = blockIdx.x * 256 + threadIdx.x;
    float m = -__builtin_inff();
    for (int r = 0; r < 512; ++r)
        m = fmaxf(m, h[((size_t)b * 512 + r) * 1024 + col]);
    g[b * 1024 + col] = m;
}

__global__ __launch_bounds__(256) void fc_kernel(const float* __restrict__ g,
                                                 const float* __restrict__ w,
                                                 const float* __restrict__ bias,
                                                 float* __restrict__ out) {
    const int b = blockIdx.x, c = threadIdx.x;
    float acc = bias[c];
    for (int k = 0; k < 1024; ++k)
        acc = fmaf(g[b * 1024 + k], w[(size_t)k * 256 + c], acc);
    out[b * 256 + c] = acc;
}

// ---------------------------------------------------------------------------
extern "C" void kernel_launch(void* const* d_in, const int* in_sizes, int n_in,
                              void* d_out, int out_size, void* d_ws, size_t ws_size,
                              hipStream_t stream) {
    const float* data  = (const float*)d_in[0];
    const float* s1w1  = (const float*)d_in[1];
    const float* s1b1  = (const float*)d_in[2];
    const float* s1w2  = (const float*)d_in[3];
    const float* s1b2  = (const float*)d_in[4];
    const float* s1w3  = (const float*)d_in[5];
    const float* s1b3  = (const float*)d_in[6];
    const float* s2w1  = (const float*)d_in[7];
    const float* s2b1  = (const float*)d_in[8];
    const float* s2w2  = (const float*)d_in[9];
    const float* s2b2  = (const float*)d_in[10];
    const float* s2w3  = (const float*)d_in[11];
    const float* s2b3  = (const float*)d_in[12];
    const float* s3w1  = (const float*)d_in[13];
    const float* s3b1  = (const float*)d_in[14];
    const float* s3w2  = (const float*)d_in[15];
    const float* s3b2  = (const float*)d_in[16];
    const float* s3w3  = (const float*)d_in[17];
    const float* s3b3  = (const float*)d_in[18];
    const float* fcw   = (const float*)d_in[19];
    const float* fcb   = (const float*)d_in[20];
    float* out = (float*)d_out;

    char* ws = (char*)d_ws;
    size_t o = 0;
    auto nxt = [&](size_t bytes) {
        size_t r = o;
        o += (bytes + 255) & ~(size_t)255;
        return r;
    };
    float* pos1 = (float*)(ws + nxt(4 * 2048 * 3 * 4));
    float* pos2 = (float*)(ws + nxt(4 * 512 * 3 * 4));
    int*   nbr1 = (int*)(ws + nxt((size_t)8192 * 64 * 4));
    int*   cnt1 = (int*)(ws + nxt(8192 * 4));
    int*   nbr2 = (int*)(ws + nxt((size_t)2048 * 64 * 4));
    int*   cnt2 = (int*)(ws + nxt(2048 * 4));
    float* x1   = (float*)(ws + nxt((size_t)8192 * 128 * 4));
    float* x2   = (float*)(ws + nxt((size_t)2048 * 256 * 4));
    float* xin3 = (float*)(ws + nxt((size_t)2048 * 259 * 4));
    float* h1   = (float*)(ws + nxt((size_t)2048 * 256 * 4));
    float* h2   = (float*)(ws + nxt((size_t)2048 * 512 * 4));
    float* h3   = (float*)(ws + nxt((size_t)2048 * 1024 * 4));
    float* g    = (float*)(ws + nxt(4 * 1024 * 4));

    const float R1SQ = (float)(0.2 * 0.2);  // matches JAX weak-scalar f32 cast
    const float R2SQ = (float)(0.4 * 0.4);

    fps_kernel<<<4, 512, 0, stream>>>(data, pos1, pos2);
    nbr_kernel<4096, 1024><<<2048, 256, 0, stream>>>(data, pos1, 2048, R1SQ, nbr1, cnt1);
    nbr_kernel<2048, 1536><<<512, 256, 0, stream>>>(pos1, pos2, 512, R2SQ, nbr2, cnt2);
    mlp1_kernel<<<8192, 256, 0, stream>>>(data, pos1, nbr1, cnt1,
                                          s1w1, s1b1, s1w2, s1b2, s1w3, s1b3, x1);
    mlp2_kernel<<<2048, 256, 0, stream>>>(x1, pos1, pos2, nbr2, cnt2,
                                          s2w1, s2b1, s2w2, s2b2, s2w3, s2b3, x2);
    pack3_kernel<<<2048, 64, 0, stream>>>(x2, pos2, xin3);
    gemm_kernel<<<dim3(4, 32), 256, 0, stream>>>(xin3, s3w1, s3b1, h1, 2048, 259, 256, 1);
    gemm_kernel<<<dim3(8, 32), 256, 0, stream>>>(h1, s3w2, s3b2, h2, 2048, 256, 512, 1);
    gemm_kernel<<<dim3(16, 32), 256, 0, stream>>>(h2, s3w3, s3b3, h3, 2048, 512, 1024, 0);
    maxpool_kernel<<<dim3(4, 4), 256, 0, stream>>>(h3, g);
    fc_kernel<<<4, 256, 0, stream>>>(g, fcw, fcb, out);
}

// Round 5
// 3651.608 us; speedup vs baseline: 1.2417x; 1.2417x over previous
//
#include <hip/hip_runtime.h>

// ---------------------------------------------------------------------------
// PointNet++ (SSG) forward on MI355X.
// B=4, N=4096. sa1: S1=2048 r=0.2 K=64, MLP 6-64-64-128.
//              sa2: S2=512  r=0.4 K=64, MLP 131-128-128-256.
//              sa3: MLP 259-256-512-1024 + global max. fc: 1024->256.
// All discrete decisions (FPS argmax, radius membership, top-64 rank) are
// computed with bitwise-exact f32 ops matching the reference association
// order; __f*_rn intrinsics block FMA contraction.
// FPS argmax uses u64-packed (f32bits<<32 | ~idx) keys: for non-negative f32,
// uint compare == float compare, and ~idx gives smaller-index-wins on ties --
// exactly jnp.argmax semantics.
// NOTE (r4 post-mortem): ext_vector v2f "packed" math REGRESSED fps 1680->2348
// (scalarized + extra select tree). Keep the r3 u64-tree form.
// ---------------------------------------------------------------------------

#define DEVFN __device__ __forceinline__

DEVFN float d2_exact(float ax, float ay, float az, float bx, float by, float bz) {
    float dx = __fsub_rn(ax, bx);
    float dy = __fsub_rn(ay, by);
    float dz = __fsub_rn(az, bz);
    return __fadd_rn(__fadd_rn(__fmul_rn(dx, dx), __fmul_rn(dy, dy)), __fmul_rn(dz, dz));
}

DEVFN unsigned long long u64max(unsigned long long a, unsigned long long b) {
    return a > b ? a : b;
}

// DPP rotate-right by R within each 16-lane row (all lanes valid -> no
// bound_ctrl concerns). Applied to a u64 as two 32-bit halves.
template <int R>
DEVFN unsigned long long dpp_ror16_u64(unsigned long long x) {
    int lo = (int)(unsigned)(x & 0xFFFFFFFFull);
    int hi = (int)(unsigned)(x >> 32);
    lo = __builtin_amdgcn_update_dpp(lo, lo, 0x120 | R, 0xF, 0xF, false);
    hi = __builtin_amdgcn_update_dpp(hi, hi, 0x120 | R, 0xF, 0xF, false);
    return ((unsigned long long)(unsigned)hi << 32) | (unsigned)lo;
}

// readlane both halves of a u64 from a fixed lane -> wave-uniform value
DEVFN unsigned long long rl_u64(unsigned long long x, int lane) {
    unsigned l = (unsigned)__builtin_amdgcn_readlane((int)(unsigned)(x & 0xFFFFFFFFull), lane);
    unsigned h = (unsigned)__builtin_amdgcn_readlane((int)(unsigned)(x >> 32), lane);
    return ((unsigned long long)h << 32) | l;
}

// ---------------------------------------------------------------------------
// FPS (both stages fused; one 512-thread block per cloud). r3 structure.
// ---------------------------------------------------------------------------
template <int N, int S, int NT>
DEVFN void run_fps(const float* sx, const float* sy, const float* sz,
                   unsigned long long* sPack,  // [2][NT/64]
                   int* selLds) {
    constexpr int PPT = N / NT;
    constexpr int NW = NT / 64;
    const int tid = threadIdx.x;
    float px[PPT], py[PPT], pz[PPT], md[PPT];
    unsigned loc[PPT];
#pragma unroll
    for (int i = 0; i < PPT; ++i) {
        int idx = tid * PPT + i;
        px[i] = sx[idx]; py[i] = sy[idx]; pz[i] = sz[idx];
        md[i] = __builtin_inff();  // first pass (cur=0) produces dist-to-point-0
        loc[i] = 0xFFFFFFFFu - (unsigned)idx;  // ~global_index
    }
    if (tid == 0) selLds[0] = 0;
    int cur = 0;
    for (int s = 1; s < S; ++s) {
        float ax = sx[cur], ay = sy[cur], az = sz[cur];  // uniform LDS broadcast
        unsigned long long tq[PPT];
#pragma unroll
        for (int i = 0; i < PPT; ++i) {
            float d = d2_exact(px[i], py[i], pz[i], ax, ay, az);
            float m = fminf(md[i], d);
            md[i] = m;
            tq[i] = ((unsigned long long)__float_as_uint(m) << 32) |
                    (unsigned long long)loc[i];
        }
#pragma unroll
        for (int w = PPT / 2; w >= 1; w >>= 1)
#pragma unroll
            for (int i = 0; i < w; ++i) tq[i] = u64max(tq[i], tq[i + w]);

        unsigned long long pk = tq[0];
        pk = u64max(pk, dpp_ror16_u64<8>(pk));
        pk = u64max(pk, dpp_ror16_u64<4>(pk));
        pk = u64max(pk, dpp_ror16_u64<2>(pk));
        pk = u64max(pk, dpp_ror16_u64<1>(pk));  // each 16-lane row: row max

        // cross-row combine via readlane (wave-uniform result)
        unsigned long long wmax = u64max(u64max(rl_u64(pk, 0), rl_u64(pk, 16)),
                                         u64max(rl_u64(pk, 32), rl_u64(pk, 48)));

        unsigned long long* sp = sPack + (s & 1) * NW;
        if ((tid & 63) == 0) sp[tid >> 6] = wmax;
        __syncthreads();

        const ulonglong2* sp2 = (const ulonglong2*)sp;  // NW=8 -> 4 x b128
        ulonglong2 q0 = sp2[0], q1 = sp2[1], q2 = sp2[2], q3 = sp2[3];
        unsigned long long m01 = u64max(u64max(q0.x, q0.y), u64max(q1.x, q1.y));
        unsigned long long m23 = u64max(u64max(q2.x, q2.y), u64max(q3.x, q3.y));
        unsigned long long win = u64max(m01, m23);

        cur = (int)(0xFFFFFFFFu - (unsigned)(win & 0xFFFFFFFFull));
        if (tid == 0) selLds[s] = cur;
        // no second barrier: next iteration writes the other parity slot set,
        // and the following barrier orders reuse.
    }
}

__global__ __launch_bounds__(512) void fps_kernel(const float* __restrict__ data,
                                                  float* __restrict__ pos1,
                                                  float* __restrict__ pos2) {
    __shared__ __align__(16) float sx[4096];
    __shared__ __align__(16) float sy[4096];
    __shared__ __align__(16) float sz[4096];
    __shared__ __align__(16) unsigned long long sPack[16];  // [2][8]
    __shared__ int sSel1[2048];
    __shared__ int sSel2[512];

    const int b = blockIdx.x, tid = threadIdx.x;
    const float* p = data + (size_t)b * 4096 * 3;
    for (int i = tid; i < 4096; i += 512) {
        sx[i] = p[i * 3 + 0]; sy[i] = p[i * 3 + 1]; sz[i] = p[i * 3 + 2];
    }
    __syncthreads();

    run_fps<4096, 2048, 512>(sx, sy, sz, sPack, sSel1);
    __syncthreads();

    // gather pos1 and compact LDS SoA to the first 2048 slots (stage-2 input)
    float gx[4], gy[4], gz[4];
#pragma unroll
    for (int i = 0; i < 4; ++i) {
        int si = sSel1[tid * 4 + i];
        gx[i] = sx[si]; gy[i] = sy[si]; gz[i] = sz[si];
    }
    __syncthreads();
    float* p1 = pos1 + (size_t)b * 2048 * 3;
#pragma unroll
    for (int i = 0; i < 4; ++i) {
        int o = tid * 4 + i;
        sx[o] = gx[i]; sy[o] = gy[i]; sz[o] = gz[i];
        p1[o * 3 + 0] = gx[i]; p1[o * 3 + 1] = gy[i]; p1[o * 3 + 2] = gz[i];
    }
    __syncthreads();

    run_fps<2048, 512, 512>(sx, sy, sz, sPack, sSel2);
    __syncthreads();

    float* p2 = pos2 + (size_t)b * 512 * 3;
    {
        int si = sSel2[tid];
        p2[tid * 3 + 0] = sx[si]; p2[tid * 3 + 1] = sy[si]; p2[tid * 3 + 2] = sz[si];
    }
}

// ---------------------------------------------------------------------------
// Radius neighbors, exact top-64 by (d2 asc, idx asc) -- one wave per center
// ---------------------------------------------------------------------------
template <int N, int CAP>
__global__ __launch_bounds__(256) void nbr_kernel(const float* __restrict__ pos,  // [B][N][3]
                                                  const float* __restrict__ ctr,  // [B*S][3]
                                                  const int S, const float rsq,
                                                  int* __restrict__ nbr,          // [B*S][64]
                                                  int* __restrict__ cnt) {
    __shared__ float sD[4][CAP];
    __shared__ int   sI[4][CAP];
    const int wid = threadIdx.x >> 6, lane = threadIdx.x & 63;
    const int c = blockIdx.x * 4 + wid;
    const int b = c / S;
    const float* p = pos + (size_t)b * N * 3;
    const float cx = ctr[(size_t)c * 3 + 0];
    const float cy = ctr[(size_t)c * 3 + 1];
    const float cz = ctr[(size_t)c * 3 + 2];

    int count = 0;  // wave-uniform
    for (int j = lane; j < N; j += 64) {
        float d = d2_exact(cx, cy, cz, p[j * 3 + 0], p[j * 3 + 1], p[j * 3 + 2]);
        bool pred = (d <= rsq);
        unsigned long long m = __ballot(pred);
        int wpos = count + __popcll(m & ((1ull << lane) - 1ull));
        if (pred && wpos < CAP) { sD[wid][wpos] = d; sI[wid][wpos] = j; }
        count += __popcll(m);
    }
    if (count > CAP) count = CAP;

    for (int t = lane; t < count; t += 64) {
        float d = sD[wid][t]; int id = sI[wid][t];
        int rank = 0;
        for (int j0 = 0; j0 < count; ++j0) {
            float dj = sD[wid][j0]; int ij = sI[wid][j0];
            rank += (dj < d || (dj == d && ij < id)) ? 1 : 0;
        }
        if (rank < 64) nbr[(size_t)c * 64 + rank] = id;
    }
    if (lane == 0) cnt[c] = count < 64 ? count : 64;
}

// ---------------------------------------------------------------------------
// Register-tile FMA helpers (A from LDS, W from LDS; float4 k-blocks)
// ---------------------------------------------------------------------------
DEVFN void tile44_fma(const float* __restrict__ aBase, int aStride,
                      const float* __restrict__ wBase, int wStride,
                      int nk4, float (&acc)[4][4]) {
    for (int k4 = 0; k4 < nk4; ++k4) {
        float a[4][4], w[4][4];
#pragma unroll
        for (int i = 0; i < 4; ++i) {
            float4 t = *(const float4*)(aBase + i * aStride + k4 * 4);
            a[i][0] = t.x; a[i][1] = t.y; a[i][2] = t.z; a[i][3] = t.w;
        }
#pragma unroll
        for (int kk = 0; kk < 4; ++kk) {
            float4 t = *(const float4*)(wBase + (k4 * 4 + kk) * wStride);
            w[kk][0] = t.x; w[kk][1] = t.y; w[kk][2] = t.z; w[kk][3] = t.w;
        }
#pragma unroll
        for (int kk = 0; kk < 4; ++kk)
#pragma unroll
            for (int i = 0; i < 4; ++i)
#pragma unroll
                for (int j = 0; j < 4; ++j)
                    acc[i][j] = fmaf(a[i][kk], w[kk][j], acc[i][j]);
    }
}

DEVFN void tile48_fma(const float* __restrict__ aBase, int aStride,
                      const float* __restrict__ wBase, int wStride,
                      int nk4, float (&acc)[4][8]) {
    for (int k4 = 0; k4 < nk4; ++k4) {
        float a[4][4];
#pragma unroll
        for (int i = 0; i < 4; ++i) {
            float4 t = *(const float4*)(aBase + i * aStride + k4 * 4);
            a[i][0] = t.x; a[i][1] = t.y; a[i][2] = t.z; a[i][3] = t.w;
        }
#pragma unroll
        for (int kk = 0; kk < 4; ++kk) {
            float4 t0 = *(const float4*)(wBase + (k4 * 4 + kk) * wStride);
            float4 t1 = *(const float4*)(wBase + (k4 * 4 + kk) * wStride + 4);
            float w_[8] = {t0.x, t0.y, t0.z, t0.w, t1.x, t1.y, t1.z, t1.w};
#pragma unroll
            for (int i = 0; i < 4; ++i)
#pragma unroll
                for (int j = 0; j < 8; ++j)
                    acc[i][j] = fmaf(a[i][kk], w_[j], acc[i][j]);
        }
    }
}

// ---------------------------------------------------------------------------
// sa1 MLP: feats[64][6] -> 64 -> 64 -> 128, masked max over rows. Block/center.
// ---------------------------------------------------------------------------
__global__ __launch_bounds__(256) void mlp1_kernel(
    const float* __restrict__ pos,   // [B][4096][3]
    const float* __restrict__ ctr,   // [8192][3]
    const int* __restrict__ nbr, const int* __restrict__ cnt,
    const float* __restrict__ w1, const float* __restrict__ b1,
    const float* __restrict__ w2, const float* __restrict__ b2,
    const float* __restrict__ w3, const float* __restrict__ b3,
    float* __restrict__ x1)          // [8192][128]
{
    __shared__ __align__(16) float smem[15424];
    float* sFeat = smem;            // [64][9]   (576)
    float* sW    = smem + 576;      // w2 [64][64]=4096 ; layer3: w3 [64][128]=8192 (spills over dead sH1)
    float* sH1   = smem + 4672;     // [64][68]  (4352)
    float* sH2   = smem + 9024;     // [64][68]  (4352)
    float* sRed  = smem + 13376;    // [16][128] (2048)

    const int tid = threadIdx.x;
    const int c = blockIdx.x;
    const int b = c >> 11;          // / 2048
    const int valid = cnt[c];

    if (tid < 64) {
        const int r = tid;
        float fx = 0.f, fy = 0.f, fz = 0.f, dx = 0.f, dy = 0.f, dz = 0.f;
        if (r < valid) {
            int j = nbr[(size_t)c * 64 + r];
            const float* pj = pos + ((size_t)b * 4096 + j) * 3;
            fx = pj[0]; fy = pj[1]; fz = pj[2];
            dx = fx - ctr[c * 3 + 0]; dy = fy - ctr[c * 3 + 1]; dz = fz - ctr[c * 3 + 2];
        }
        float* fr = sFeat + r * 9;
        fr[0] = fx; fr[1] = fy; fr[2] = fz; fr[3] = dx; fr[4] = dy; fr[5] = dz;
    }
    for (int l = tid; l < 4096; l += 256) sW[l] = w2[l];
    __syncthreads();

    // layer1: [64][6] @ [6][64] + b1, relu
    {
        const int r = tid & 63, c0 = (tid >> 6) * 16;
        float acc[16];
#pragma unroll
        for (int q = 0; q < 16; ++q) acc[q] = b1[c0 + q];
#pragma unroll
        for (int k = 0; k < 6; ++k) {
            float a = sFeat[r * 9 + k];
#pragma unroll
            for (int q = 0; q < 16; ++q) acc[q] = fmaf(a, w1[k * 64 + c0 + q], acc[q]);
        }
        float* hr = sH1 + r * 68 + c0;
#pragma unroll
        for (int q = 0; q < 16; ++q) hr[q] = fmaxf(acc[q], 0.f);
    }
    __syncthreads();

    // layer2: [64][64] @ [64][64] + b2, relu
    {
        const int r0 = (tid >> 4) * 4, c0 = (tid & 15) * 4;
        float acc[4][4];
#pragma unroll
        for (int i = 0; i < 4; ++i)
#pragma unroll
            for (int j = 0; j < 4; ++j) acc[i][j] = b2[c0 + j];
        tile44_fma(sH1 + r0 * 68, 68, sW + c0, 64, 16, acc);
#pragma unroll
        for (int i = 0; i < 4; ++i)
#pragma unroll
            for (int j = 0; j < 4; ++j)
                sH2[(r0 + i) * 68 + c0 + j] = fmaxf(acc[i][j], 0.f);
    }
    __syncthreads();

    // layer3: [64][64] @ [64][128], masked max over valid rows, + b3
    for (int l = tid; l < 8192; l += 256) sW[l] = w3[l];
    __syncthreads();
    {
        const int r0 = (tid >> 4) * 4, c0 = (tid & 15) * 8;
        float acc[4][8];
#pragma unroll
        for (int i = 0; i < 4; ++i)
#pragma unroll
            for (int j = 0; j < 8; ++j) acc[i][j] = 0.f;
        tile48_fma(sH2 + r0 * 68, 68, sW + c0, 128, 16, acc);
        float pm[8];
#pragma unroll
        for (int j = 0; j < 8; ++j) pm[j] = -__builtin_inff();
#pragma unroll
        for (int i = 0; i < 4; ++i)
            if (r0 + i < valid)
#pragma unroll
                for (int j = 0; j < 8; ++j) pm[j] = fmaxf(pm[j], acc[i][j]);
#pragma unroll
        for (int j = 0; j < 8; ++j) sRed[(tid >> 4) * 128 + c0 + j] = pm[j];
    }
    __syncthreads();
    if (tid < 128) {
        float m = -__builtin_inff();
#pragma unroll
        for (int g = 0; g < 16; ++g) m = fmaxf(m, sRed[g * 128 + tid]);
        x1[(size_t)c * 128 + tid] = m + b3[tid];
    }
}

// ---------------------------------------------------------------------------
// sa2 MLP: feats[64][131] -> 128 -> 128 -> 256, masked max. Block/center,
// ONE 64-row pass, 512 threads, dynamic LDS (116736 B).
// ---------------------------------------------------------------------------
__global__ __launch_bounds__(512) void mlp2_kernel(
    const float* __restrict__ x1,    // [B*2048][128]
    const float* __restrict__ pos1,  // [B*2048][3]
    const float* __restrict__ ctr,   // [2048][3]
    const int* __restrict__ nbr, const int* __restrict__ cnt,
    const float* __restrict__ w1, const float* __restrict__ b1,
    const float* __restrict__ w2, const float* __restrict__ b2,
    const float* __restrict__ w3, const float* __restrict__ b3,
    float* __restrict__ x2)          // [2048][256]
{
    extern __shared__ float smem[];
    float* sF   = smem;              // [64][132] feats, then h2   (8448)
    float* sH   = smem + 8448;       // [64][132] h1               (8448)
    float* sW   = smem + 16896;      // weight tile, up to [32][256] (8192)
    float* sRed = smem + 25088;      // [16][256]                  (4096)

    const int tid = threadIdx.x;
    const int c = blockIdx.x;
    const int b = c >> 9;            // / 512
    const int valid = cnt[c];
    const float cx = ctr[c * 3 + 0], cy = ctr[c * 3 + 1], cz = ctr[c * 3 + 2];

    // load feats [64][132]: 8 loader-threads per row
    {
        const int r = tid >> 3, t8 = tid & 7;
        float* fr = sF + r * 132;
        if (r < valid) {
            int j = nbr[(size_t)c * 64 + r];
            const float* xp = x1 + ((size_t)b * 2048 + j) * 128;
#pragma unroll
            for (int q = 0; q < 4; ++q) {
                float4 v = *(const float4*)(xp + t8 * 16 + q * 4);
                fr[t8 * 16 + q * 4 + 0] = v.x; fr[t8 * 16 + q * 4 + 1] = v.y;
                fr[t8 * 16 + q * 4 + 2] = v.z; fr[t8 * 16 + q * 4 + 3] = v.w;
            }
            if (t8 == 0) {
                const float* pj = pos1 + ((size_t)b * 2048 + j) * 3;
                fr[128] = pj[0] - cx; fr[129] = pj[1] - cy; fr[130] = pj[2] - cz;
                fr[131] = 0.f;
            }
        } else {
#pragma unroll
            for (int q = 0; q < 16; ++q) fr[t8 * 16 + q] = 0.f;
            if (t8 == 0) { fr[128] = 0.f; fr[129] = 0.f; fr[130] = 0.f; fr[131] = 0.f; }
        }
    }
    __syncthreads();

    const int r0 = (tid >> 5) * 4;        // 16 row-groups x 4 rows
    const int c0 = (tid & 31) * 4;        // 32 col-groups x 4 cols (l1/l2)
    const int c8 = (tid & 31) * 8;        // 32 col-groups x 8 cols (l3)

    // layer1: [64][131(pad132)] @ [131][128] + b1, relu -> sH
    {
        float acc[4][4];
#pragma unroll
        for (int i = 0; i < 4; ++i)
#pragma unroll
            for (int j = 0; j < 4; ++j) acc[i][j] = b1[c0 + j];
        for (int kb = 0; kb < 132; kb += 32) {
            const int kt = (132 - kb) < 32 ? (132 - kb) : 32;  // 32,32,32,32,4
            for (int l = tid; l < kt * 128; l += 512) {
                int k = l >> 7, cc = l & 127;
                sW[k * 128 + cc] = (kb + k < 131) ? w1[(size_t)(kb + k) * 128 + cc] : 0.f;
            }
            __syncthreads();
            tile44_fma(sF + r0 * 132 + kb, 132, sW + c0, 128, kt / 4, acc);
            __syncthreads();
        }
#pragma unroll
        for (int i = 0; i < 4; ++i)
#pragma unroll
            for (int j = 0; j < 4; ++j)
                sH[(r0 + i) * 132 + c0 + j] = fmaxf(acc[i][j], 0.f);
    }
    __syncthreads();

    // layer2: K=128, sH -> sF (h2), relu
    {
        float acc[4][4];
#pragma unroll
        for (int i = 0; i < 4; ++i)
#pragma unroll
            for (int j = 0; j < 4; ++j) acc[i][j] = b2[c0 + j];
        for (int kb = 0; kb < 128; kb += 32) {
            for (int l = tid; l < 32 * 128; l += 512) {
                int k = l >> 7, cc = l & 127;
                sW[k * 128 + cc] = w2[(size_t)(kb + k) * 128 + cc];
            }
            __syncthreads();
            tile44_fma(sH + r0 * 132 + kb, 132, sW + c0, 128, 8, acc);
            __syncthreads();
        }
#pragma unroll
        for (int i = 0; i < 4; ++i)
#pragma unroll
            for (int j = 0; j < 4; ++j)
                sF[(r0 + i) * 132 + c0 + j] = fmaxf(acc[i][j], 0.f);
    }
    __syncthreads();

    // layer3: K=128, cols=256, masked col-max
    {
        float acc[4][8];
#pragma unroll
        for (int i = 0; i < 4; ++i)
#pragma unroll
            for (int j = 0; j < 8; ++j) acc[i][j] = 0.f;
        for (int kb = 0; kb < 128; kb += 32) {
            for (int l = tid; l < 32 * 256; l += 512) {
                int k = l >> 8, cc = l & 255;
                sW[k * 256 + cc] = w3[(size_t)(kb + k) * 256 + cc];
            }
            __syncthreads();
            tile48_fma(sF + r0 * 132 + kb, 132, sW + c8, 256, 8, acc);
            __syncthreads();
        }
        float pm[8];
#pragma unroll
        for (int j = 0; j < 8; ++j) pm[j] = -__builtin_inff();
#pragma unroll
        for (int i = 0; i < 4; ++i)
            if (r0 + i < valid)
#pragma unroll
                for (int j = 0; j < 8; ++j) pm[j] = fmaxf(pm[j], acc[i][j]);
#pragma unroll
        for (int j = 0; j < 8; ++j) sRed[(tid >> 5) * 256 + c8 + j] = pm[j];
    }
    __syncthreads();
    if (tid < 256) {
        float m = -__builtin_inff();
#pragma unroll
        for (int g = 0; g < 16; ++g) m = fmaxf(m, sRed[g * 256 + tid]);
        x2[(size_t)c * 256 + tid] = m + b3[tid];
    }
}

// ---------------------------------------------------------------------------
// sa3: pack cat([x2,pos2]) -> 3 GEMMs -> max-pool -> fc
// ---------------------------------------------------------------------------
__global__ __launch_bounds__(64) void pack3_kernel(const float* __restrict__ x2,
                                                   const float* __restrict__ pos2,
                                                   float* __restrict__ xin) {
    const int row = blockIdx.x, tid = threadIdx.x;
    for (int cc = tid; cc < 259; cc += 64)
        xin[(size_t)row * 259 + cc] = (cc < 256) ? x2[(size_t)row * 256 + cc]
                                                 : pos2[row * 3 + (cc - 256)];
}

__global__ __launch_bounds__(256) void gemm_kernel(const float* __restrict__ A,
                                                   const float* __restrict__ W,
                                                   const float* __restrict__ bias,
                                                   float* __restrict__ C,
                                                   int M, int K, int Nc, int relu) {
    __shared__ __align__(16) float sA[64 * 36];
    __shared__ __align__(16) float sB[32 * 68];
    const int tid = threadIdx.x;
    const int row0 = blockIdx.y * 64, col0 = blockIdx.x * 64;
    const int r0 = (tid >> 4) * 4, c0 = (tid & 15) * 4;
    float acc[4][4];
#pragma unroll
    for (int i = 0; i < 4; ++i)
#pragma unroll
        for (int j = 0; j < 4; ++j) acc[i][j] = 0.f;

    for (int kb = 0; kb < K; kb += 32) {
        for (int l = tid; l < 64 * 32; l += 256) {
            int r = l >> 5, k = l & 31;
            sA[r * 36 + k] = (kb + k < K) ? A[(size_t)(row0 + r) * K + kb + k] : 0.f;
        }
        for (int l = tid; l < 32 * 64; l += 256) {
            int k = l >> 6, cc = l & 63;
            sB[k * 68 + cc] = (kb + k < K) ? W[(size_t)(kb + k) * Nc + col0 + cc] : 0.f;
        }
        __syncthreads();
        tile44_fma(sA + r0 * 36, 36, sB + c0, 68, 8, acc);
        __syncthreads();
    }
#pragma unroll
    for (int i = 0; i < 4; ++i)
#pragma unroll
        for (int j = 0; j < 4; ++j) {
            float v = acc[i][j] + bias[col0 + c0 + j];
            if (relu) v = fmaxf(v, 0.f);
            C[(size_t)(row0 + r0 + i) * Nc + col0 + c0 + j] = v;
        }
}

__global__ __launch_bounds__(256) void maxpool_kernel(const float* __restrict__ h,
                                                      float* __restrict__ g) {
    const int b = blockIdx.y, col = blockIdx.x * 256 + threadIdx.x;
    float m = -__builtin_inff();
    for (int r = 0; r < 512; ++r)
        m = fmaxf(m, h[((size_t)b * 512 + r) * 1024 + col]);
    g[b * 1024 + col] = m;
}

__global__ __launch_bounds__(256) void fc_kernel(const float* __restrict__ g,
                                                 const float* __restrict__ w,
                                                 const float* __restrict__ bias,
                                                 float* __restrict__ out) {
    const int b = blockIdx.x, c = threadIdx.x;
    float acc = bias[c];
    for (int k = 0; k < 1024; ++k)
        acc = fmaf(g[b * 1024 + k], w[(size_t)k * 256 + c], acc);
    out[b * 256 + c] = acc;
}

// ---------------------------------------------------------------------------
extern "C" void kernel_launch(void* const* d_in, const int* in_sizes, int n_in,
                              void* d_out, int out_size, void* d_ws, size_t ws_size,
                              hipStream_t stream) {
    const float* data  = (const float*)d_in[0];
    const float* s1w1  = (const float*)d_in[1];
    const float* s1b1  = (const float*)d_in[2];
    const float* s1w2  = (const float*)d_in[3];
    const float* s1b2  = (const float*)d_in[4];
    const float* s1w3  = (const float*)d_in[5];
    const float* s1b3  = (const float*)d_in[6];
    const float* s2w1  = (const float*)d_in[7];
    const float* s2b1  = (const float*)d_in[8];
    const float* s2w2  = (const float*)d_in[9];
    const float* s2b2  = (const float*)d_in[10];
    const float* s2w3  = (const float*)d_in[11];
    const float* s2b3  = (const float*)d_in[12];
    const float* s3w1  = (const float*)d_in[13];
    const float* s3b1  = (const float*)d_in[14];
    const float* s3w2  = (const float*)d_in[15];
    const float* s3b2  = (const float*)d_in[16];
    const float* s3w3  = (const float*)d_in[17];
    const float* s3b3  = (const float*)d_in[18];
    const float* fcw   = (const float*)d_in[19];
    const float* fcb   = (const float*)d_in[20];
    float* out = (float*)d_out;

    char* ws = (char*)d_ws;
    size_t o = 0;
    auto nxt = [&](size_t bytes) {
        size_t r = o;
        o += (bytes + 255) & ~(size_t)255;
        return r;
    };
    float* pos1 = (float*)(ws + nxt(4 * 2048 * 3 * 4));
    float* pos2 = (float*)(ws + nxt(4 * 512 * 3 * 4));
    int*   nbr1 = (int*)(ws + nxt((size_t)8192 * 64 * 4));
    int*   cnt1 = (int*)(ws + nxt(8192 * 4));
    int*   nbr2 = (int*)(ws + nxt((size_t)2048 * 64 * 4));
    int*   cnt2 = (int*)(ws + nxt(2048 * 4));
    float* x1   = (float*)(ws + nxt((size_t)8192 * 128 * 4));
    float* x2   = (float*)(ws + nxt((size_t)2048 * 256 * 4));
    float* xin3 = (float*)(ws + nxt((size_t)2048 * 259 * 4));
    float* h1   = (float*)(ws + nxt((size_t)2048 * 256 * 4));
    float* h2   = (float*)(ws + nxt((size_t)2048 * 512 * 4));
    float* h3   = (float*)(ws + nxt((size_t)2048 * 1024 * 4));
    float* g    = (float*)(ws + nxt(4 * 1024 * 4));

    const float R1SQ = (float)(0.2 * 0.2);  // matches JAX weak-scalar f32 cast
    const float R2SQ = (float)(0.4 * 0.4);

    fps_kernel<<<4, 512, 0, stream>>>(data, pos1, pos2);
    nbr_kernel<4096, 1024><<<2048, 256, 0, stream>>>(data, pos1, 2048, R1SQ, nbr1, cnt1);
    nbr_kernel<2048, 1536><<<512, 256, 0, stream>>>(pos1, pos2, 512, R2SQ, nbr2, cnt2);
    mlp1_kernel<<<8192, 256, 0, stream>>>(data, pos1, nbr1, cnt1,
                                          s1w1, s1b1, s1w2, s1b2, s1w3, s1b3, x1);
    mlp2_kernel<<<2048, 512, 116736, stream>>>(x1, pos1, pos2, nbr2, cnt2,
                                               s2w1, s2b1, s2w2, s2b2, s2w3, s2b3, x2);
    pack3_kernel<<<2048, 64, 0, stream>>>(x2, pos2, xin3);
    gemm_kernel<<<dim3(4, 32), 256, 0, stream>>>(xin3, s3w1, s3b1, h1, 2048, 259, 256, 1);
    gemm_kernel<<<dim3(8, 32), 256, 0, stream>>>(h1, s3w2, s3b2, h2, 2048, 256, 512, 1);
    gemm_kernel<<<dim3(16, 32), 256, 0, stream>>>(h2, s3w3, s3b3, h3, 2048, 512, 1024, 0);
    maxpool_kernel<<<dim3(4, 4), 256, 0, stream>>>(h3, g);
    fc_kernel<<<4, 256, 0, stream>>>(g, fcw, fcb, out);
}

// Round 6
// 3215.417 us; speedup vs baseline: 1.4101x; 1.1357x over previous
//
#include <hip/hip_runtime.h>

// ---------------------------------------------------------------------------
// PointNet++ (SSG) forward on MI355X.
// B=4, N=4096. sa1: S1=2048 r=0.2 K=64, MLP 6-64-64-128.
//              sa2: S2=512  r=0.4 K=64, MLP 131-128-128-256.
//              sa3: MLP 259-256-512-1024 + global max. fc: 1024->256.
// All discrete decisions (FPS argmax, radius membership, top-64 rank) are
// computed with bitwise-exact f32 ops matching the reference association
// order; __f*_rn intrinsics block FMA contraction.
// FPS argmax uses u64-packed (f32bits<<32 | ~idx) keys: for non-negative f32,
// uint compare == float compare, and ~idx gives smaller-index-wins on ties --
// exactly jnp.argmax semantics.
// r4 post-mortem: ext_vector v2f math REGRESSED fps (scalarized); keep r3 form.
// r6: fps stage2 rides in mlp1 kernel (blocks 0..3, dispatched first) to
// overlap with mlp1; nbr rank loop unrolled x4; pack3->gemm1, maxpool+fc fused.
// ---------------------------------------------------------------------------

#define DEVFN __device__ __forceinline__

DEVFN float d2_exact(float ax, float ay, float az, float bx, float by, float bz) {
    float dx = __fsub_rn(ax, bx);
    float dy = __fsub_rn(ay, by);
    float dz = __fsub_rn(az, bz);
    return __fadd_rn(__fadd_rn(__fmul_rn(dx, dx), __fmul_rn(dy, dy)), __fmul_rn(dz, dz));
}

DEVFN unsigned long long u64max(unsigned long long a, unsigned long long b) {
    return a > b ? a : b;
}

template <int R>
DEVFN unsigned long long dpp_ror16_u64(unsigned long long x) {
    int lo = (int)(unsigned)(x & 0xFFFFFFFFull);
    int hi = (int)(unsigned)(x >> 32);
    lo = __builtin_amdgcn_update_dpp(lo, lo, 0x120 | R, 0xF, 0xF, false);
    hi = __builtin_amdgcn_update_dpp(hi, hi, 0x120 | R, 0xF, 0xF, false);
    return ((unsigned long long)(unsigned)hi << 32) | (unsigned)lo;
}

DEVFN unsigned long long rl_u64(unsigned long long x, int lane) {
    unsigned l = (unsigned)__builtin_amdgcn_readlane((int)(unsigned)(x & 0xFFFFFFFFull), lane);
    unsigned h = (unsigned)__builtin_amdgcn_readlane((int)(unsigned)(x >> 32), lane);
    return ((unsigned long long)h << 32) | l;
}

// ---------------------------------------------------------------------------
// FPS core (one block; NT threads). u64-tree form (r3-validated).
// ---------------------------------------------------------------------------
template <int N, int S, int NT>
DEVFN void run_fps(const float* sx, const float* sy, const float* sz,
                   unsigned long long* sPack,  // [2][NT/64]
                   int* selLds) {
    constexpr int PPT = N / NT;
    constexpr int NW = NT / 64;
    const int tid = threadIdx.x;
    float px[PPT], py[PPT], pz[PPT], md[PPT];
    unsigned loc[PPT];
#pragma unroll
    for (int i = 0; i < PPT; ++i) {
        int idx = tid * PPT + i;
        px[i] = sx[idx]; py[i] = sy[idx]; pz[i] = sz[idx];
        md[i] = __builtin_inff();  // first pass (cur=0) produces dist-to-point-0
        loc[i] = 0xFFFFFFFFu - (unsigned)idx;  // ~global_index
    }
    if (tid == 0) selLds[0] = 0;
    int cur = 0;
    for (int s = 1; s < S; ++s) {
        float ax = sx[cur], ay = sy[cur], az = sz[cur];  // uniform LDS broadcast
        unsigned long long tq[PPT];
#pragma unroll
        for (int i = 0; i < PPT; ++i) {
            float d = d2_exact(px[i], py[i], pz[i], ax, ay, az);
            float m = fminf(md[i], d);
            md[i] = m;
            tq[i] = ((unsigned long long)__float_as_uint(m) << 32) |
                    (unsigned long long)loc[i];
        }
#pragma unroll
        for (int w = PPT / 2; w >= 1; w >>= 1)
#pragma unroll
            for (int i = 0; i < w; ++i) tq[i] = u64max(tq[i], tq[i + w]);

        unsigned long long pk = tq[0];
        pk = u64max(pk, dpp_ror16_u64<8>(pk));
        pk = u64max(pk, dpp_ror16_u64<4>(pk));
        pk = u64max(pk, dpp_ror16_u64<2>(pk));
        pk = u64max(pk, dpp_ror16_u64<1>(pk));  // each 16-lane row: row max

        unsigned long long wmax = u64max(u64max(rl_u64(pk, 0), rl_u64(pk, 16)),
                                         u64max(rl_u64(pk, 32), rl_u64(pk, 48)));

        unsigned long long* sp = sPack + (s & 1) * NW;
        if ((tid & 63) == 0) sp[tid >> 6] = wmax;
        __syncthreads();

        unsigned long long win;
        if constexpr (NW == 8) {
            const ulonglong2* sp2 = (const ulonglong2*)sp;
            ulonglong2 q0 = sp2[0], q1 = sp2[1], q2 = sp2[2], q3 = sp2[3];
            unsigned long long m01 = u64max(u64max(q0.x, q0.y), u64max(q1.x, q1.y));
            unsigned long long m23 = u64max(u64max(q2.x, q2.y), u64max(q3.x, q3.y));
            win = u64max(m01, m23);
        } else {  // NW == 4
            const ulonglong2* sp2 = (const ulonglong2*)sp;
            ulonglong2 q0 = sp2[0], q1 = sp2[1];
            win = u64max(u64max(q0.x, q0.y), u64max(q1.x, q1.y));
        }

        cur = (int)(0xFFFFFFFFu - (unsigned)(win & 0xFFFFFFFFull));
        if (tid == 0) selLds[s] = cur;
        // parity double-buffer: next iter writes the other slot set.
    }
}

// ---------------------------------------------------------------------------
// FPS stage 1 only: data -> pos1
// ---------------------------------------------------------------------------
__global__ __launch_bounds__(512) void fps_kernel(const float* __restrict__ data,
                                                  float* __restrict__ pos1) {
    __shared__ __align__(16) float sx[4096];
    __shared__ __align__(16) float sy[4096];
    __shared__ __align__(16) float sz[4096];
    __shared__ __align__(16) unsigned long long sPack[16];  // [2][8]
    __shared__ int sSel1[2048];

    const int b = blockIdx.x, tid = threadIdx.x;
    const float* p = data + (size_t)b * 4096 * 3;
    for (int i = tid; i < 4096; i += 512) {
        sx[i] = p[i * 3 + 0]; sy[i] = p[i * 3 + 1]; sz[i] = p[i * 3 + 2];
    }
    __syncthreads();

    run_fps<4096, 2048, 512>(sx, sy, sz, sPack, sSel1);
    __syncthreads();

    float* p1 = pos1 + (size_t)b * 2048 * 3;
#pragma unroll
    for (int i = 0; i < 4; ++i) {
        int o = tid * 4 + i;
        int si = sSel1[o];
        p1[o * 3 + 0] = sx[si]; p1[o * 3 + 1] = sy[si]; p1[o * 3 + 2] = sz[si];
    }
}

// ---------------------------------------------------------------------------
// Radius neighbors, exact top-64 by (d2 asc, idx asc) -- one wave per center.
// Rank loop unrolled x4 with b128 broadcast reads.
// ---------------------------------------------------------------------------
template <int N, int CAP>
__global__ __launch_bounds__(256) void nbr_kernel(const float* __restrict__ pos,  // [B][N][3]
                                                  const float* __restrict__ ctr,  // [B*S][3]
                                                  const int S, const float rsq,
                                                  int* __restrict__ nbr,          // [B*S][64]
                                                  int* __restrict__ cnt) {
    __shared__ __align__(16) float sD[4][CAP];
    __shared__ __align__(16) int   sI[4][CAP];
    const int wid = threadIdx.x >> 6, lane = threadIdx.x & 63;
    const int c = blockIdx.x * 4 + wid;
    const int b = c / S;
    const float* p = pos + (size_t)b * N * 3;
    const float cx = ctr[(size_t)c * 3 + 0];
    const float cy = ctr[(size_t)c * 3 + 1];
    const float cz = ctr[(size_t)c * 3 + 2];

    int count = 0;  // wave-uniform
    for (int j = lane; j < N; j += 64) {
        float d = d2_exact(cx, cy, cz, p[j * 3 + 0], p[j * 3 + 1], p[j * 3 + 2]);
        bool pred = (d <= rsq);
        unsigned long long m = __ballot(pred);
        int wpos = count + __popcll(m & ((1ull << lane) - 1ull));
        if (pred && wpos < CAP) { sD[wid][wpos] = d; sI[wid][wpos] = j; }
        count += __popcll(m);
    }
    if (count > CAP) count = CAP;

    for (int t = lane; t < count; t += 64) {
        float d = sD[wid][t]; int id = sI[wid][t];
        int rank = 0;
        int j0 = 0;
        for (; j0 + 4 <= count; j0 += 4) {
            float4 dj = *(const float4*)&sD[wid][j0];   // broadcast across lanes
            int4   ij = *(const int4*)&sI[wid][j0];
            rank += (dj.x < d || (dj.x == d && ij.x < id)) ? 1 : 0;
            rank += (dj.y < d || (dj.y == d && ij.y < id)) ? 1 : 0;
            rank += (dj.z < d || (dj.z == d && ij.z < id)) ? 1 : 0;
            rank += (dj.w < d || (dj.w == d && ij.w < id)) ? 1 : 0;
        }
        for (; j0 < count; ++j0) {
            float dj = sD[wid][j0]; int ij = sI[wid][j0];
            rank += (dj < d || (dj == d && ij < id)) ? 1 : 0;
        }
        if (rank < 64) nbr[(size_t)c * 64 + rank] = id;
    }
    if (lane == 0) cnt[c] = count < 64 ? count : 64;
}

// ---------------------------------------------------------------------------
// Register-tile FMA helpers (A from LDS, W from LDS; float4 k-blocks)
// ---------------------------------------------------------------------------
DEVFN void tile44_fma(const float* __restrict__ aBase, int aStride,
                      const float* __restrict__ wBase, int wStride,
                      int nk4, float (&acc)[4][4]) {
    for (int k4 = 0; k4 < nk4; ++k4) {
        float a[4][4], w[4][4];
#pragma unroll
        for (int i = 0; i < 4; ++i) {
            float4 t = *(const float4*)(aBase + i * aStride + k4 * 4);
            a[i][0] = t.x; a[i][1] = t.y; a[i][2] = t.z; a[i][3] = t.w;
        }
#pragma unroll
        for (int kk = 0; kk < 4; ++kk) {
            float4 t = *(const float4*)(wBase + (k4 * 4 + kk) * wStride);
            w[kk][0] = t.x; w[kk][1] = t.y; w[kk][2] = t.z; w[kk][3] = t.w;
        }
#pragma unroll
        for (int kk = 0; kk < 4; ++kk)
#pragma unroll
            for (int i = 0; i < 4; ++i)
#pragma unroll
                for (int j = 0; j < 4; ++j)
                    acc[i][j] = fmaf(a[i][kk], w[kk][j], acc[i][j]);
    }
}

DEVFN void tile48_fma(const float* __restrict__ aBase, int aStride,
                      const float* __restrict__ wBase, int wStride,
                      int nk4, float (&acc)[4][8]) {
    for (int k4 = 0; k4 < nk4; ++k4) {
        float a[4][4];
#pragma unroll
        for (int i = 0; i < 4; ++i) {
            float4 t = *(const float4*)(aBase + i * aStride + k4 * 4);
            a[i][0] = t.x; a[i][1] = t.y; a[i][2] = t.z; a[i][3] = t.w;
        }
#pragma unroll
        for (int kk = 0; kk < 4; ++kk) {
            float4 t0 = *(const float4*)(wBase + (k4 * 4 + kk) * wStride);
            float4 t1 = *(const float4*)(wBase + (k4 * 4 + kk) * wStride + 4);
            float w_[8] = {t0.x, t0.y, t0.z, t0.w, t1.x, t1.y, t1.z, t1.w};
#pragma unroll
            for (int i = 0; i < 4; ++i)
#pragma unroll
                for (int j = 0; j < 8; ++j)
                    acc[i][j] = fmaf(a[i][kk], w_[j], acc[i][j]);
        }
    }
}

// ---------------------------------------------------------------------------
// mlp1s2: blocks 0..3 = FPS stage2 (pos1 -> pos2, dispatched FIRST so it
// overlaps); blocks 4..8195 = sa1 MLP per center.
// ---------------------------------------------------------------------------
__global__ __launch_bounds__(256) void mlp1s2_kernel(
    const float* __restrict__ pos,   // [B][4096][3]
    const float* __restrict__ ctr,   // [8192][3] = pos1
    const int* __restrict__ nbr, const int* __restrict__ cnt,
    const float* __restrict__ w1, const float* __restrict__ b1,
    const float* __restrict__ w2, const float* __restrict__ b2,
    const float* __restrict__ w3, const float* __restrict__ b3,
    float* __restrict__ x1,          // [8192][128]
    const float* __restrict__ pos1,  // [B][2048][3] (stage2 input)
    float* __restrict__ pos2)        // [B][512][3]  (stage2 output)
{
    __shared__ __align__(16) float smem[15424];

    const int tid = threadIdx.x;

    if (blockIdx.x < 4) {
        // ---------------- FPS stage 2 ----------------
        const int b = blockIdx.x;
        float* s2x = smem;            // [2048]
        float* s2y = smem + 2048;
        float* s2z = smem + 4096;
        int*   sSel2 = (int*)(smem + 6144);                       // [512]
        unsigned long long* sPack2 = (unsigned long long*)(smem + 6656);  // [2][4]

        const float* p1 = pos1 + (size_t)b * 2048 * 3;
        for (int i = tid; i < 2048; i += 256) {
            s2x[i] = p1[i * 3 + 0]; s2y[i] = p1[i * 3 + 1]; s2z[i] = p1[i * 3 + 2];
        }
        __syncthreads();

        run_fps<2048, 512, 256>(s2x, s2y, s2z, sPack2, sSel2);
        __syncthreads();

        float* p2 = pos2 + (size_t)b * 512 * 3;
        for (int i = tid; i < 512; i += 256) {
            int si = sSel2[i];
            p2[i * 3 + 0] = s2x[si]; p2[i * 3 + 1] = s2y[si]; p2[i * 3 + 2] = s2z[si];
        }
        return;
    }

    // ---------------- sa1 MLP ----------------
    float* sFeat = smem;            // [64][9]   (576)
    float* sW    = smem + 576;      // w2 4096 ; layer3: w3 8192 (overlaps dead sH1)
    float* sH1   = smem + 4672;     // [64][68]  (4352)
    float* sH2   = smem + 9024;     // [64][68]  (4352)
    float* sRed  = smem + 13376;    // [16][128] (2048)

    const int c = blockIdx.x - 4;
    const int b = c >> 11;          // / 2048
    const int valid = cnt[c];

    if (tid < 64) {
        const int r = tid;
        float fx = 0.f, fy = 0.f, fz = 0.f, dx = 0.f, dy = 0.f, dz = 0.f;
        if (r < valid) {
            int j = nbr[(size_t)c * 64 + r];
            const float* pj = pos + ((size_t)b * 4096 + j) * 3;
            fx = pj[0]; fy = pj[1]; fz = pj[2];
            dx = fx - ctr[c * 3 + 0]; dy = fy - ctr[c * 3 + 1]; dz = fz - ctr[c * 3 + 2];
        }
        float* fr = sFeat + r * 9;
        fr[0] = fx; fr[1] = fy; fr[2] = fz; fr[3] = dx; fr[4] = dy; fr[5] = dz;
    }
    for (int l = tid; l < 4096; l += 256) sW[l] = w2[l];
    __syncthreads();

    // layer1: [64][6] @ [6][64] + b1, relu
    {
        const int r = tid & 63, c0 = (tid >> 6) * 16;
        float acc[16];
#pragma unroll
        for (int q = 0; q < 16; ++q) acc[q] = b1[c0 + q];
#pragma unroll
        for (int k = 0; k < 6; ++k) {
            float a = sFeat[r * 9 + k];
#pragma unroll
            for (int q = 0; q < 16; ++q) acc[q] = fmaf(a, w1[k * 64 + c0 + q], acc[q]);
        }
        float* hr = sH1 + r * 68 + c0;
#pragma unroll
        for (int q = 0; q < 16; ++q) hr[q] = fmaxf(acc[q], 0.f);
    }
    __syncthreads();

    // layer2: [64][64] @ [64][64] + b2, relu
    {
        const int r0 = (tid >> 4) * 4, c0 = (tid & 15) * 4;
        float acc[4][4];
#pragma unroll
        for (int i = 0; i < 4; ++i)
#pragma unroll
            for (int j = 0; j < 4; ++j) acc[i][j] = b2[c0 + j];
        tile44_fma(sH1 + r0 * 68, 68, sW + c0, 64, 16, acc);
#pragma unroll
        for (int i = 0; i < 4; ++i)
#pragma unroll
            for (int j = 0; j < 4; ++j)
                sH2[(r0 + i) * 68 + c0 + j] = fmaxf(acc[i][j], 0.f);
    }
    __syncthreads();

    // layer3: [64][64] @ [64][128], masked max over valid rows, + b3
    for (int l = tid; l < 8192; l += 256) sW[l] = w3[l];
    __syncthreads();
    {
        const int r0 = (tid >> 4) * 4, c0 = (tid & 15) * 8;
        float acc[4][8];
#pragma unroll
        for (int i = 0; i < 4; ++i)
#pragma unroll
            for (int j = 0; j < 8; ++j) acc[i][j] = 0.f;
        tile48_fma(sH2 + r0 * 68, 68, sW + c0, 128, 16, acc);
        float pm[8];
#pragma unroll
        for (int j = 0; j < 8; ++j) pm[j] = -__builtin_inff();
#pragma unroll
        for (int i = 0; i < 4; ++i)
            if (r0 + i < valid)
#pragma unroll
                for (int j = 0; j < 8; ++j) pm[j] = fmaxf(pm[j], acc[i][j]);
#pragma unroll
        for (int j = 0; j < 8; ++j) sRed[(tid >> 4) * 128 + c0 + j] = pm[j];
    }
    __syncthreads();
    if (tid < 128) {
        float m = -__builtin_inff();
#pragma unroll
        for (int g = 0; g < 16; ++g) m = fmaxf(m, sRed[g * 128 + tid]);
        x1[(size_t)c * 128 + tid] = m + b3[tid];
    }
}

// ---------------------------------------------------------------------------
// sa2 MLP: ONE 64-row pass, 512 threads, dynamic LDS (116736 B).
// ---------------------------------------------------------------------------
__global__ __launch_bounds__(512) void mlp2_kernel(
    const float* __restrict__ x1,    // [B*2048][128]
    const float* __restrict__ pos1,  // [B*2048][3]
    const float* __restrict__ ctr,   // [2048][3]
    const int* __restrict__ nbr, const int* __restrict__ cnt,
    const float* __restrict__ w1, const float* __restrict__ b1,
    const float* __restrict__ w2, const float* __restrict__ b2,
    const float* __restrict__ w3, const float* __restrict__ b3,
    float* __restrict__ x2)          // [2048][256]
{
    extern __shared__ float smem[];
    float* sF   = smem;              // [64][132] feats, then h2   (8448)
    float* sH   = smem + 8448;       // [64][132] h1               (8448)
    float* sW   = smem + 16896;      // weight tile, up to [32][256] (8192)
    float* sRed = smem + 25088;      // [16][256]                  (4096)

    const int tid = threadIdx.x;
    const int c = blockIdx.x;
    const int b = c >> 9;            // / 512
    const int valid = cnt[c];
    const float cx = ctr[c * 3 + 0], cy = ctr[c * 3 + 1], cz = ctr[c * 3 + 2];

    {
        const int r = tid >> 3, t8 = tid & 7;
        float* fr = sF + r * 132;
        if (r < valid) {
            int j = nbr[(size_t)c * 64 + r];
            const float* xp = x1 + ((size_t)b * 2048 + j) * 128;
#pragma unroll
            for (int q = 0; q < 4; ++q) {
                float4 v = *(const float4*)(xp + t8 * 16 + q * 4);
                fr[t8 * 16 + q * 4 + 0] = v.x; fr[t8 * 16 + q * 4 + 1] = v.y;
                fr[t8 * 16 + q * 4 + 2] = v.z; fr[t8 * 16 + q * 4 + 3] = v.w;
            }
            if (t8 == 0) {
                const float* pj = pos1 + ((size_t)b * 2048 + j) * 3;
                fr[128] = pj[0] - cx; fr[129] = pj[1] - cy; fr[130] = pj[2] - cz;
                fr[131] = 0.f;
            }
        } else {
#pragma unroll
            for (int q = 0; q < 16; ++q) fr[t8 * 16 + q] = 0.f;
            if (t8 == 0) { fr[128] = 0.f; fr[129] = 0.f; fr[130] = 0.f; fr[131] = 0.f; }
        }
    }
    __syncthreads();

    const int r0 = (tid >> 5) * 4;
    const int c0 = (tid & 31) * 4;
    const int c8 = (tid & 31) * 8;

    // layer1
    {
        float acc[4][4];
#pragma unroll
        for (int i = 0; i < 4; ++i)
#pragma unroll
            for (int j = 0; j < 4; ++j) acc[i][j] = b1[c0 + j];
        for (int kb = 0; kb < 132; kb += 32) {
            const int kt = (132 - kb) < 32 ? (132 - kb) : 32;
            for (int l = tid; l < kt * 128; l += 512) {
                int k = l >> 7, cc = l & 127;
                sW[k * 128 + cc] = (kb + k < 131) ? w1[(size_t)(kb + k) * 128 + cc] : 0.f;
            }
            __syncthreads();
            tile44_fma(sF + r0 * 132 + kb, 132, sW + c0, 128, kt / 4, acc);
            __syncthreads();
        }
#pragma unroll
        for (int i = 0; i < 4; ++i)
#pragma unroll
            for (int j = 0; j < 4; ++j)
                sH[(r0 + i) * 132 + c0 + j] = fmaxf(acc[i][j], 0.f);
    }
    __syncthreads();

    // layer2
    {
        float acc[4][4];
#pragma unroll
        for (int i = 0; i < 4; ++i)
#pragma unroll
            for (int j = 0; j < 4; ++j) acc[i][j] = b2[c0 + j];
        for (int kb = 0; kb < 128; kb += 32) {
            for (int l = tid; l < 32 * 128; l += 512) {
                int k = l >> 7, cc = l & 127;
                sW[k * 128 + cc] = w2[(size_t)(kb + k) * 128 + cc];
            }
            __syncthreads();
            tile44_fma(sH + r0 * 132 + kb, 132, sW + c0, 128, 8, acc);
            __syncthreads();
        }
#pragma unroll
        for (int i = 0; i < 4; ++i)
#pragma unroll
            for (int j = 0; j < 4; ++j)
                sF[(r0 + i) * 132 + c0 + j] = fmaxf(acc[i][j], 0.f);
    }
    __syncthreads();

    // layer3 + masked col-max
    {
        float acc[4][8];
#pragma unroll
        for (int i = 0; i < 4; ++i)
#pragma unroll
            for (int j = 0; j < 8; ++j) acc[i][j] = 0.f;
        for (int kb = 0; kb < 128; kb += 32) {
            for (int l = tid; l < 32 * 256; l += 512) {
                int k = l >> 8, cc = l & 255;
                sW[k * 256 + cc] = w3[(size_t)(kb + k) * 256 + cc];
            }
            __syncthreads();
            tile48_fma(sF + r0 * 132 + kb, 132, sW + c8, 256, 8, acc);
            __syncthreads();
        }
        float pm[8];
#pragma unroll
        for (int j = 0; j < 8; ++j) pm[j] = -__builtin_inff();
#pragma unroll
        for (int i = 0; i < 4; ++i)
            if (r0 + i < valid)
#pragma unroll
                for (int j = 0; j < 8; ++j) pm[j] = fmaxf(pm[j], acc[i][j]);
#pragma unroll
        for (int j = 0; j < 8; ++j) sRed[(tid >> 5) * 256 + c8 + j] = pm[j];
    }
    __syncthreads();
    if (tid < 256) {
        float m = -__builtin_inff();
#pragma unroll
        for (int g = 0; g < 16; ++g) m = fmaxf(m, sRed[g * 256 + tid]);
        x2[(size_t)c * 256 + tid] = m + b3[tid];
    }
}

// ---------------------------------------------------------------------------
// gemm1f: A = cat([x2, pos2]) built on the fly (pack3 fused). K=259, relu.
// ---------------------------------------------------------------------------
__global__ __launch_bounds__(256) void gemm1f_kernel(const float* __restrict__ x2,
                                                     const float* __restrict__ pos2,
                                                     const float* __restrict__ W,
                                                     const float* __restrict__ bias,
                                                     float* __restrict__ C) {
    constexpr int K = 259, Nc = 256;
    __shared__ __align__(16) float sA[64 * 36];
    __shared__ __align__(16) float sB[32 * 68];
    const int tid = threadIdx.x;
    const int row0 = blockIdx.y * 64, col0 = blockIdx.x * 64;
    const int r0 = (tid >> 4) * 4, c0 = (tid & 15) * 4;
    float acc[4][4];
#pragma unroll
    for (int i = 0; i < 4; ++i)
#pragma unroll
        for (int j = 0; j < 4; ++j) acc[i][j] = 0.f;

    for (int kb = 0; kb < K; kb += 32) {
        for (int l = tid; l < 64 * 32; l += 256) {
            int r = l >> 5, k = l & 31;
            int gk = kb + k;
            float av = 0.f;
            if (gk < K) {
                int row = row0 + r;
                av = (gk < 256) ? x2[(size_t)row * 256 + gk]
                                : pos2[row * 3 + (gk - 256)];
            }
            sA[r * 36 + k] = av;
        }
        for (int l = tid; l < 32 * 64; l += 256) {
            int k = l >> 6, cc = l & 63;
            sB[k * 68 + cc] = (kb + k < K) ? W[(size_t)(kb + k) * Nc + col0 + cc] : 0.f;
        }
        __syncthreads();
        tile44_fma(sA + r0 * 36, 36, sB + c0, 68, 8, acc);
        __syncthreads();
    }
#pragma unroll
    for (int i = 0; i < 4; ++i)
#pragma unroll
        for (int j = 0; j < 4; ++j)
            C[(size_t)(row0 + r0 + i) * Nc + col0 + c0 + j] =
                fmaxf(acc[i][j] + bias[col0 + c0 + j], 0.f);
}

__global__ __launch_bounds__(256) void gemm_kernel(const float* __restrict__ A,
                                                   const float* __restrict__ W,
                                                   const float* __restrict__ bias,
                                                   float* __restrict__ C,
                                                   int M, int K, int Nc, int relu) {
    __shared__ __align__(16) float sA[64 * 36];
    __shared__ __align__(16) float sB[32 * 68];
    const int tid = threadIdx.x;
    const int row0 = blockIdx.y * 64, col0 = blockIdx.x * 64;
    const int r0 = (tid >> 4) * 4, c0 = (tid & 15) * 4;
    float acc[4][4];
#pragma unroll
    for (int i = 0; i < 4; ++i)
#pragma unroll
        for (int j = 0; j < 4; ++j) acc[i][j] = 0.f;

    for (int kb = 0; kb < K; kb += 32) {
        for (int l = tid; l < 64 * 32; l += 256) {
            int r = l >> 5, k = l & 31;
            sA[r * 36 + k] = (kb + k < K) ? A[(size_t)(row0 + r) * K + kb + k] : 0.f;
        }
        for (int l = tid; l < 32 * 64; l += 256) {
            int k = l >> 6, cc = l & 63;
            sB[k * 68 + cc] = (kb + k < K) ? W[(size_t)(kb + k) * Nc + col0 + cc] : 0.f;
        }
        __syncthreads();
        tile44_fma(sA + r0 * 36, 36, sB + c0, 68, 8, acc);
        __syncthreads();
    }
#pragma unroll
    for (int i = 0; i < 4; ++i)
#pragma unroll
        for (int j = 0; j < 4; ++j) {
            float v = acc[i][j] + bias[col0 + c0 + j];
            if (relu) v = fmaxf(v, 0.f);
            C[(size_t)(row0 + r0 + i) * Nc + col0 + c0 + j] = v;
        }
}

// ---------------------------------------------------------------------------
// maxpool over 512 rows + fc (1024->256), fused: one block per batch.
// ---------------------------------------------------------------------------
__global__ __launch_bounds__(1024) void mpfc_kernel(const float* __restrict__ h,
                                                    const float* __restrict__ w,
                                                    const float* __restrict__ bias,
                                                    float* __restrict__ out) {
    __shared__ float sG[1024];
    __shared__ float sP[4][256];
    const int b = blockIdx.x, tid = threadIdx.x;

    float m = -__builtin_inff();
    const float* hp = h + (size_t)b * 512 * 1024 + tid;
    for (int r = 0; r < 512; ++r) m = fmaxf(m, hp[(size_t)r * 1024]);
    sG[tid] = m;
    __syncthreads();

    const int c = tid & 255, kc = tid >> 8;  // 4 k-chunks of 256
    float acc = 0.f;
    const float* wp = w + (size_t)(kc * 256) * 256 + c;
    const float* gp = sG + kc * 256;
    for (int k = 0; k < 256; ++k) acc = fmaf(gp[k], wp[(size_t)k * 256], acc);
    sP[kc][c] = acc;
    __syncthreads();
    if (tid < 256)
        out[b * 256 + tid] = ((sP[0][tid] + sP[1][tid]) + (sP[2][tid] + sP[3][tid]))
                             + bias[tid];
}

// ---------------------------------------------------------------------------
extern "C" void kernel_launch(void* const* d_in, const int* in_sizes, int n_in,
                              void* d_out, int out_size, void* d_ws, size_t ws_size,
                              hipStream_t stream) {
    const float* data  = (const float*)d_in[0];
    const float* s1w1  = (const float*)d_in[1];
    const float* s1b1  = (const float*)d_in[2];
    const float* s1w2  = (const float*)d_in[3];
    const float* s1b2  = (const float*)d_in[4];
    const float* s1w3  = (const float*)d_in[5];
    const float* s1b3  = (const float*)d_in[6];
    const float* s2w1  = (const float*)d_in[7];
    const float* s2b1  = (const float*)d_in[8];
    const float* s2w2  = (const float*)d_in[9];
    const float* s2b2  = (const float*)d_in[10];
    const float* s2w3  = (const float*)d_in[11];
    const float* s2b3  = (const float*)d_in[12];
    const float* s3w1  = (const float*)d_in[13];
    const float* s3b1  = (const float*)d_in[14];
    const float* s3w2  = (const float*)d_in[15];
    const float* s3b2  = (const float*)d_in[16];
    const float* s3w3  = (const float*)d_in[17];
    const float* s3b3  = (const float*)d_in[18];
    const float* fcw   = (const float*)d_in[19];
    const float* fcb   = (const float*)d_in[20];
    float* out = (float*)d_out;

    char* ws = (char*)d_ws;
    size_t o = 0;
    auto nxt = [&](size_t bytes) {
        size_t r = o;
        o += (bytes + 255) & ~(size_t)255;
        return r;
    };
    float* pos1 = (float*)(ws + nxt(4 * 2048 * 3 * 4));
    float* pos2 = (float*)(ws + nxt(4 * 512 * 3 * 4));
    int*   nbr1 = (int*)(ws + nxt((size_t)8192 * 64 * 4));
    int*   cnt1 = (int*)(ws + nxt(8192 * 4));
    int*   nbr2 = (int*)(ws + nxt((size_t)2048 * 64 * 4));
    int*   cnt2 = (int*)(ws + nxt(2048 * 4));
    float* x1   = (float*)(ws + nxt((size_t)8192 * 128 * 4));
    float* x2   = (float*)(ws + nxt((size_t)2048 * 256 * 4));
    float* h1   = (float*)(ws + nxt((size_t)2048 * 256 * 4));
    float* h2   = (float*)(ws + nxt((size_t)2048 * 512 * 4));
    float* h3   = (float*)(ws + nxt((size_t)2048 * 1024 * 4));

    const float R1SQ = (float)(0.2 * 0.2);  // matches JAX weak-scalar f32 cast
    const float R2SQ = (float)(0.4 * 0.4);

    fps_kernel<<<4, 512, 0, stream>>>(data, pos1);
    nbr_kernel<4096, 1024><<<2048, 256, 0, stream>>>(data, pos1, 2048, R1SQ, nbr1, cnt1);
    mlp1s2_kernel<<<8196, 256, 0, stream>>>(data, pos1, nbr1, cnt1,
                                            s1w1, s1b1, s1w2, s1b2, s1w3, s1b3, x1,
                                            pos1, pos2);
    nbr_kernel<2048, 1536><<<512, 256, 0, stream>>>(pos1, pos2, 512, R2SQ, nbr2, cnt2);
    mlp2_kernel<<<2048, 512, 116736, stream>>>(x1, pos1, pos2, nbr2, cnt2,
                                               s2w1, s2b1, s2w2, s2b2, s2w3, s2b3, x2);
    gemm1f_kernel<<<dim3(4, 32), 256, 0, stream>>>(x2, pos2, s3w1, s3b1, h1);
    gemm_kernel<<<dim3(8, 32), 256, 0, stream>>>(h1, s3w2, s3b2, h2, 2048, 256, 512, 1);
    gemm_kernel<<<dim3(16, 32), 256, 0, stream>>>(h2, s3w3, s3b3, h3, 2048, 512, 1024, 0);
    mpfc_kernel<<<4, 1024, 0, stream>>>(h3, fcw, fcb, out);
}

// Round 7
// 3195.553 us; speedup vs baseline: 1.4189x; 1.0062x over previous
//
#include <hip/hip_runtime.h>

// ---------------------------------------------------------------------------
// PointNet++ (SSG) forward on MI355X.
// B=4, N=4096. sa1: S1=2048 r=0.2 K=64, MLP 6-64-64-128.
//              sa2: S2=512  r=0.4 K=64, MLP 131-128-128-256.
//              sa3: MLP 259-256-512-1024 + global max. fc: 1024->256.
// All discrete decisions (FPS argmax, radius membership, top-64 rank) are
// computed with bitwise-exact f32 ops matching the reference association
// order; __f*_rn intrinsics block FMA contraction.
// FPS argmax key = (f32bits<<32 | ~idx): for non-negative f32, uint compare ==
// float compare; ~idx gives smaller-index-wins on ties (jnp.argmax).
// r4 post-mortem: ext_vector v2f math REGRESSED fps (scalarized); keep scalar.
// r7: fps stage1 split into 4 chunk kernels (md/sel persisted in ws) to
// surface the hidden non-fps kernels in top-5 profiling; per-point selection
// switched to fmax-tree + backward == scan (exact; fewer inst than u64 tree).
// ---------------------------------------------------------------------------

#define DEVFN __device__ __forceinline__

DEVFN float d2_exact(float ax, float ay, float az, float bx, float by, float bz) {
    float dx = __fsub_rn(ax, bx);
    float dy = __fsub_rn(ay, by);
    float dz = __fsub_rn(az, bz);
    return __fadd_rn(__fadd_rn(__fmul_rn(dx, dx), __fmul_rn(dy, dy)), __fmul_rn(dz, dz));
}

DEVFN unsigned long long u64max(unsigned long long a, unsigned long long b) {
    return a > b ? a : b;
}

template <int R>
DEVFN unsigned long long dpp_ror16_u64(unsigned long long x) {
    int lo = (int)(unsigned)(x & 0xFFFFFFFFull);
    int hi = (int)(unsigned)(x >> 32);
    lo = __builtin_amdgcn_update_dpp(lo, lo, 0x120 | R, 0xF, 0xF, false);
    hi = __builtin_amdgcn_update_dpp(hi, hi, 0x120 | R, 0xF, 0xF, false);
    return ((unsigned long long)(unsigned)hi << 32) | (unsigned)lo;
}

DEVFN unsigned long long rl_u64(unsigned long long x, int lane) {
    unsigned l = (unsigned)__builtin_amdgcn_readlane((int)(unsigned)(x & 0xFFFFFFFFull), lane);
    unsigned h = (unsigned)__builtin_amdgcn_readlane((int)(unsigned)(x >> 32), lane);
    return ((unsigned long long)h << 32) | l;
}

// ---------------------------------------------------------------------------
// FPS stage-1 chunk kernel: iterations [sb, se) of 2048, md/sel persisted.
// One 512-thread block per cloud. Per iteration: dist+min (8 pts/thread),
// fmax tree + backward == scan -> per-lane (max, smallest-local-idx), single
// u64 key, 4x DPP row_ror + readlane -> per-wave winner -> LDS (parity
// double-buffered), ONE barrier, combine 8 keys.
// ---------------------------------------------------------------------------
__global__ __launch_bounds__(512) void fps_chunk_kernel(
    const float* __restrict__ data,   // [B][4096][3]
    float* __restrict__ mdG,          // [B][4096]
    int* __restrict__ selG,           // [B][2048]
    float* __restrict__ pos1,         // [B][2048][3]
    const int sb, const int se)       // sb>=1
{
    constexpr int N = 4096, NT = 512, PPT = N / NT, NW = NT / 64;
    __shared__ __align__(16) float sx[N];
    __shared__ __align__(16) float sy[N];
    __shared__ __align__(16) float sz[N];
    __shared__ __align__(16) unsigned long long sPack[16];  // [2][8]
    __shared__ int sSel[512];

    const int b = blockIdx.x, tid = threadIdx.x;
    const float* p = data + (size_t)b * N * 3;
    for (int i = tid; i < N; i += NT) {
        sx[i] = p[i * 3 + 0]; sy[i] = p[i * 3 + 1]; sz[i] = p[i * 3 + 2];
    }
    __syncthreads();

    float px[PPT], py[PPT], pz[PPT], md[PPT];
    const bool first = (sb == 1);
#pragma unroll
    for (int i = 0; i < PPT; ++i) {
        int idx = tid * PPT + i;
        px[i] = sx[idx]; py[i] = sy[idx]; pz[i] = sz[idx];
        md[i] = first ? __builtin_inff() : mdG[(size_t)b * N + idx];
    }
    int cur = first ? 0 : selG[(size_t)b * 2048 + sb - 1];
    if (first && tid == 0) selG[(size_t)b * 2048] = 0;
    const unsigned lob = 0xFFFFFFFFu - (unsigned)(tid * PPT);  // ~(tid*PPT)

    for (int s = sb; s < se; ++s) {
        float ax = sx[cur], ay = sy[cur], az = sz[cur];  // uniform LDS broadcast
        float mm[PPT];
#pragma unroll
        for (int i = 0; i < PPT; ++i) {
            float d = d2_exact(px[i], py[i], pz[i], ax, ay, az);
            float m = fminf(md[i], d);
            md[i] = m; mm[i] = m;
        }
        // fmax tree (non-destructive) + backward == scan: smallest local idx
        // among ties -> identical ordering to the u64 (~idx) key within lane.
        float a0 = fmaxf(mm[0], mm[4]), a1 = fmaxf(mm[1], mm[5]);
        float a2 = fmaxf(mm[2], mm[6]), a3 = fmaxf(mm[3], mm[7]);
        float b0 = fmaxf(a0, a2), b1 = fmaxf(a1, a3);
        float mloc = fmaxf(b0, b1);
        int li = 7;
#pragma unroll
        for (int i = 6; i >= 0; --i) li = (mm[i] == mloc) ? i : li;

        unsigned long long k0 =
            ((unsigned long long)__float_as_uint(mloc) << 32) |
            (unsigned long long)(lob - (unsigned)li);

        k0 = u64max(k0, dpp_ror16_u64<8>(k0));
        k0 = u64max(k0, dpp_ror16_u64<4>(k0));
        k0 = u64max(k0, dpp_ror16_u64<2>(k0));
        k0 = u64max(k0, dpp_ror16_u64<1>(k0));  // each 16-lane row: row max

        unsigned long long wmax = u64max(u64max(rl_u64(k0, 0), rl_u64(k0, 16)),
                                         u64max(rl_u64(k0, 32), rl_u64(k0, 48)));

        unsigned long long* sp = sPack + (s & 1) * NW;
        if ((tid & 63) == 0) sp[tid >> 6] = wmax;
        __syncthreads();

        const ulonglong2* sp2 = (const ulonglong2*)sp;
        ulonglong2 q0 = sp2[0], q1 = sp2[1], q2 = sp2[2], q3 = sp2[3];
        unsigned long long m01 = u64max(u64max(q0.x, q0.y), u64max(q1.x, q1.y));
        unsigned long long m23 = u64max(u64max(q2.x, q2.y), u64max(q3.x, q3.y));
        unsigned long long win = u64max(m01, m23);

        cur = (int)(0xFFFFFFFFu - (unsigned)(win & 0xFFFFFFFFull));
        if (tid == 0) sSel[s - sb] = cur;
        // parity double-buffer: next iter writes the other slot set.
    }
    __syncthreads();

    // persist md (not needed after the last chunk, but cheap and uniform)
    if (se < 2048) {
#pragma unroll
        for (int i = 0; i < PPT; ++i)
            mdG[(size_t)b * N + tid * PPT + i] = md[i];
    }
    if (tid == 0) selG[(size_t)b * 2048 + se - 1] = cur;

    // gather this chunk's pos1 rows
    float* p1 = pos1 + (size_t)b * 2048 * 3;
    const int sb0 = first ? 0 : sb;
    for (int s = sb0 + tid; s < se; s += NT) {
        int idx = (s == 0) ? 0 : sSel[s - sb];
        p1[s * 3 + 0] = sx[idx]; p1[s * 3 + 1] = sy[idx]; p1[s * 3 + 2] = sz[idx];
    }
}

// ---------------------------------------------------------------------------
// FPS core for stage 2 (unchanged r3-validated u64-tree form; 256 threads)
// ---------------------------------------------------------------------------
template <int N, int S, int NT>
DEVFN void run_fps(const float* sx, const float* sy, const float* sz,
                   unsigned long long* sPack,  // [2][NT/64]
                   int* selLds) {
    constexpr int PPT = N / NT;
    constexpr int NW = NT / 64;
    const int tid = threadIdx.x;
    float px[PPT], py[PPT], pz[PPT], md[PPT];
    unsigned loc[PPT];
#pragma unroll
    for (int i = 0; i < PPT; ++i) {
        int idx = tid * PPT + i;
        px[i] = sx[idx]; py[i] = sy[idx]; pz[i] = sz[idx];
        md[i] = __builtin_inff();
        loc[i] = 0xFFFFFFFFu - (unsigned)idx;
    }
    if (tid == 0) selLds[0] = 0;
    int cur = 0;
    for (int s = 1; s < S; ++s) {
        float ax = sx[cur], ay = sy[cur], az = sz[cur];
        unsigned long long tq[PPT];
#pragma unroll
        for (int i = 0; i < PPT; ++i) {
            float d = d2_exact(px[i], py[i], pz[i], ax, ay, az);
            float m = fminf(md[i], d);
            md[i] = m;
            tq[i] = ((unsigned long long)__float_as_uint(m) << 32) |
                    (unsigned long long)loc[i];
        }
#pragma unroll
        for (int w = PPT / 2; w >= 1; w >>= 1)
#pragma unroll
            for (int i = 0; i < w; ++i) tq[i] = u64max(tq[i], tq[i + w]);

        unsigned long long pk = tq[0];
        pk = u64max(pk, dpp_ror16_u64<8>(pk));
        pk = u64max(pk, dpp_ror16_u64<4>(pk));
        pk = u64max(pk, dpp_ror16_u64<2>(pk));
        pk = u64max(pk, dpp_ror16_u64<1>(pk));

        unsigned long long wmax = u64max(u64max(rl_u64(pk, 0), rl_u64(pk, 16)),
                                         u64max(rl_u64(pk, 32), rl_u64(pk, 48)));

        unsigned long long* sp = sPack + (s & 1) * NW;
        if ((tid & 63) == 0) sp[tid >> 6] = wmax;
        __syncthreads();

        unsigned long long win;
        if constexpr (NW == 8) {
            const ulonglong2* sp2 = (const ulonglong2*)sp;
            ulonglong2 q0 = sp2[0], q1 = sp2[1], q2 = sp2[2], q3 = sp2[3];
            unsigned long long m01 = u64max(u64max(q0.x, q0.y), u64max(q1.x, q1.y));
            unsigned long long m23 = u64max(u64max(q2.x, q2.y), u64max(q3.x, q3.y));
            win = u64max(m01, m23);
        } else {  // NW == 4
            const ulonglong2* sp2 = (const ulonglong2*)sp;
            ulonglong2 q0 = sp2[0], q1 = sp2[1];
            win = u64max(u64max(q0.x, q0.y), u64max(q1.x, q1.y));
        }

        cur = (int)(0xFFFFFFFFu - (unsigned)(win & 0xFFFFFFFFull));
        if (tid == 0) selLds[s] = cur;
    }
}

// ---------------------------------------------------------------------------
// Radius neighbors, exact top-64 by (d2 asc, idx asc) -- one wave per center.
// ---------------------------------------------------------------------------
template <int N, int CAP>
__global__ __launch_bounds__(256) void nbr_kernel(const float* __restrict__ pos,
                                                  const float* __restrict__ ctr,
                                                  const int S, const float rsq,
                                                  int* __restrict__ nbr,
                                                  int* __restrict__ cnt) {
    __shared__ __align__(16) float sD[4][CAP];
    __shared__ __align__(16) int   sI[4][CAP];
    const int wid = threadIdx.x >> 6, lane = threadIdx.x & 63;
    const int c = blockIdx.x * 4 + wid;
    const int b = c / S;
    const float* p = pos + (size_t)b * N * 3;
    const float cx = ctr[(size_t)c * 3 + 0];
    const float cy = ctr[(size_t)c * 3 + 1];
    const float cz = ctr[(size_t)c * 3 + 2];

    int count = 0;
    for (int j = lane; j < N; j += 64) {
        float d = d2_exact(cx, cy, cz, p[j * 3 + 0], p[j * 3 + 1], p[j * 3 + 2]);
        bool pred = (d <= rsq);
        unsigned long long m = __ballot(pred);
        int wpos = count + __popcll(m & ((1ull << lane) - 1ull));
        if (pred && wpos < CAP) { sD[wid][wpos] = d; sI[wid][wpos] = j; }
        count += __popcll(m);
    }
    if (count > CAP) count = CAP;

    for (int t = lane; t < count; t += 64) {
        float d = sD[wid][t]; int id = sI[wid][t];
        int rank = 0;
        int j0 = 0;
        for (; j0 + 4 <= count; j0 += 4) {
            float4 dj = *(const float4*)&sD[wid][j0];
            int4   ij = *(const int4*)&sI[wid][j0];
            rank += (dj.x < d || (dj.x == d && ij.x < id)) ? 1 : 0;
            rank += (dj.y < d || (dj.y == d && ij.y < id)) ? 1 : 0;
            rank += (dj.z < d || (dj.z == d && ij.z < id)) ? 1 : 0;
            rank += (dj.w < d || (dj.w == d && ij.w < id)) ? 1 : 0;
        }
        for (; j0 < count; ++j0) {
            float dj = sD[wid][j0]; int ij = sI[wid][j0];
            rank += (dj < d || (dj == d && ij < id)) ? 1 : 0;
        }
        if (rank < 64) nbr[(size_t)c * 64 + rank] = id;
    }
    if (lane == 0) cnt[c] = count < 64 ? count : 64;
}

// ---------------------------------------------------------------------------
// Register-tile FMA helpers (A from LDS, W from LDS; float4 k-blocks)
// ---------------------------------------------------------------------------
DEVFN void tile44_fma(const float* __restrict__ aBase, int aStride,
                      const float* __restrict__ wBase, int wStride,
                      int nk4, float (&acc)[4][4]) {
    for (int k4 = 0; k4 < nk4; ++k4) {
        float a[4][4], w[4][4];
#pragma unroll
        for (int i = 0; i < 4; ++i) {
            float4 t = *(const float4*)(aBase + i * aStride + k4 * 4);
            a[i][0] = t.x; a[i][1] = t.y; a[i][2] = t.z; a[i][3] = t.w;
        }
#pragma unroll
        for (int kk = 0; kk < 4; ++kk) {
            float4 t = *(const float4*)(wBase + (k4 * 4 + kk) * wStride);
            w[kk][0] = t.x; w[kk][1] = t.y; w[kk][2] = t.z; w[kk][3] = t.w;
        }
#pragma unroll
        for (int kk = 0; kk < 4; ++kk)
#pragma unroll
            for (int i = 0; i < 4; ++i)
#pragma unroll
                for (int j = 0; j < 4; ++j)
                    acc[i][j] = fmaf(a[i][kk], w[kk][j], acc[i][j]);
    }
}

DEVFN void tile48_fma(const float* __restrict__ aBase, int aStride,
                      const float* __restrict__ wBase, int wStride,
                      int nk4, float (&acc)[4][8]) {
    for (int k4 = 0; k4 < nk4; ++k4) {
        float a[4][4];
#pragma unroll
        for (int i = 0; i < 4; ++i) {
            float4 t = *(const float4*)(aBase + i * aStride + k4 * 4);
            a[i][0] = t.x; a[i][1] = t.y; a[i][2] = t.z; a[i][3] = t.w;
        }
#pragma unroll
        for (int kk = 0; kk < 4; ++kk) {
            float4 t0 = *(const float4*)(wBase + (k4 * 4 + kk) * wStride);
            float4 t1 = *(const float4*)(wBase + (k4 * 4 + kk) * wStride + 4);
            float w_[8] = {t0.x, t0.y, t0.z, t0.w, t1.x, t1.y, t1.z, t1.w};
#pragma unroll
            for (int i = 0; i < 4; ++i)
#pragma unroll
                for (int j = 0; j < 8; ++j)
                    acc[i][j] = fmaf(a[i][kk], w_[j], acc[i][j]);
        }
    }
}

// ---------------------------------------------------------------------------
// mlp1s2: blocks 0..3 = FPS stage2 (pos1 -> pos2, dispatched FIRST so it
// overlaps); blocks 4..8195 = sa1 MLP per center.
// ---------------------------------------------------------------------------
__global__ __launch_bounds__(256) void mlp1s2_kernel(
    const float* __restrict__ pos,   // [B][4096][3]
    const float* __restrict__ ctr,   // [8192][3] = pos1
    const int* __restrict__ nbr, const int* __restrict__ cnt,
    const float* __restrict__ w1, const float* __restrict__ b1,
    const float* __restrict__ w2, const float* __restrict__ b2,
    const float* __restrict__ w3, const float* __restrict__ b3,
    float* __restrict__ x1,          // [8192][128]
    const float* __restrict__ pos1,  // [B][2048][3]
    float* __restrict__ pos2)        // [B][512][3]
{
    __shared__ __align__(16) float smem[15424];

    const int tid = threadIdx.x;

    if (blockIdx.x < 4) {
        const int b = blockIdx.x;
        float* s2x = smem;
        float* s2y = smem + 2048;
        float* s2z = smem + 4096;
        int*   sSel2 = (int*)(smem + 6144);
        unsigned long long* sPack2 = (unsigned long long*)(smem + 6656);

        const float* p1 = pos1 + (size_t)b * 2048 * 3;
        for (int i = tid; i < 2048; i += 256) {
            s2x[i] = p1[i * 3 + 0]; s2y[i] = p1[i * 3 + 1]; s2z[i] = p1[i * 3 + 2];
        }
        __syncthreads();

        run_fps<2048, 512, 256>(s2x, s2y, s2z, sPack2, sSel2);
        __syncthreads();

        float* p2 = pos2 + (size_t)b * 512 * 3;
        for (int i = tid; i < 512; i += 256) {
            int si = sSel2[i];
            p2[i * 3 + 0] = s2x[si]; p2[i * 3 + 1] = s2y[si]; p2[i * 3 + 2] = s2z[si];
        }
        return;
    }

    float* sFeat = smem;            // [64][9]   (576)
    float* sW    = smem + 576;      // w2 4096 ; layer3: w3 8192
    float* sH1   = smem + 4672;     // [64][68]
    float* sH2   = smem + 9024;     // [64][68]
    float* sRed  = smem + 13376;    // [16][128]

    const int c = blockIdx.x - 4;
    const int b = c >> 11;
    const int valid = cnt[c];

    if (tid < 64) {
        const int r = tid;
        float fx = 0.f, fy = 0.f, fz = 0.f, dx = 0.f, dy = 0.f, dz = 0.f;
        if (r < valid) {
            int j = nbr[(size_t)c * 64 + r];
            const float* pj = pos + ((size_t)b * 4096 + j) * 3;
            fx = pj[0]; fy = pj[1]; fz = pj[2];
            dx = fx - ctr[c * 3 + 0]; dy = fy - ctr[c * 3 + 1]; dz = fz - ctr[c * 3 + 2];
        }
        float* fr = sFeat + r * 9;
        fr[0] = fx; fr[1] = fy; fr[2] = fz; fr[3] = dx; fr[4] = dy; fr[5] = dz;
    }
    for (int l = tid; l < 4096; l += 256) sW[l] = w2[l];
    __syncthreads();

    {
        const int r = tid & 63, c0 = (tid >> 6) * 16;
        float acc[16];
#pragma unroll
        for (int q = 0; q < 16; ++q) acc[q] = b1[c0 + q];
#pragma unroll
        for (int k = 0; k < 6; ++k) {
            float a = sFeat[r * 9 + k];
#pragma unroll
            for (int q = 0; q < 16; ++q) acc[q] = fmaf(a, w1[k * 64 + c0 + q], acc[q]);
        }
        float* hr = sH1 + r * 68 + c0;
#pragma unroll
        for (int q = 0; q < 16; ++q) hr[q] = fmaxf(acc[q], 0.f);
    }
    __syncthreads();

    {
        const int r0 = (tid >> 4) * 4, c0 = (tid & 15) * 4;
        float acc[4][4];
#pragma unroll
        for (int i = 0; i < 4; ++i)
#pragma unroll
            for (int j = 0; j < 4; ++j) acc[i][j] = b2[c0 + j];
        tile44_fma(sH1 + r0 * 68, 68, sW + c0, 64, 16, acc);
#pragma unroll
        for (int i = 0; i < 4; ++i)
#pragma unroll
            for (int j = 0; j < 4; ++j)
                sH2[(r0 + i) * 68 + c0 + j] = fmaxf(acc[i][j], 0.f);
    }
    __syncthreads();

    for (int l = tid; l < 8192; l += 256) sW[l] = w3[l];
    __syncthreads();
    {
        const int r0 = (tid >> 4) * 4, c0 = (tid & 15) * 8;
        float acc[4][8];
#pragma unroll
        for (int i = 0; i < 4; ++i)
#pragma unroll
            for (int j = 0; j < 8; ++j) acc[i][j] = 0.f;
        tile48_fma(sH2 + r0 * 68, 68, sW + c0, 128, 16, acc);
        float pm[8];
#pragma unroll
        for (int j = 0; j < 8; ++j) pm[j] = -__builtin_inff();
#pragma unroll
        for (int i = 0; i < 4; ++i)
            if (r0 + i < valid)
#pragma unroll
                for (int j = 0; j < 8; ++j) pm[j] = fmaxf(pm[j], acc[i][j]);
#pragma unroll
        for (int j = 0; j < 8; ++j) sRed[(tid >> 4) * 128 + c0 + j] = pm[j];
    }
    __syncthreads();
    if (tid < 128) {
        float m = -__builtin_inff();
#pragma unroll
        for (int g = 0; g < 16; ++g) m = fmaxf(m, sRed[g * 128 + tid]);
        x1[(size_t)c * 128 + tid] = m + b3[tid];
    }
}

// ---------------------------------------------------------------------------
// sa2 MLP: ONE 64-row pass, 512 threads, dynamic LDS (116736 B).
// ---------------------------------------------------------------------------
__global__ __launch_bounds__(512) void mlp2_kernel(
    const float* __restrict__ x1,
    const float* __restrict__ pos1,
    const float* __restrict__ ctr,
    const int* __restrict__ nbr, const int* __restrict__ cnt,
    const float* __restrict__ w1, const float* __restrict__ b1,
    const float* __restrict__ w2, const float* __restrict__ b2,
    const float* __restrict__ w3, const float* __restrict__ b3,
    float* __restrict__ x2)
{
    extern __shared__ float smem[];
    float* sF   = smem;              // [64][132]
    float* sH   = smem + 8448;       // [64][132]
    float* sW   = smem + 16896;      // [32][256] max
    float* sRed = smem + 25088;      // [16][256]

    const int tid = threadIdx.x;
    const int c = blockIdx.x;
    const int b = c >> 9;
    const int valid = cnt[c];
    const float cx = ctr[c * 3 + 0], cy = ctr[c * 3 + 1], cz = ctr[c * 3 + 2];

    {
        const int r = tid >> 3, t8 = tid & 7;
        float* fr = sF + r * 132;
        if (r < valid) {
            int j = nbr[(size_t)c * 64 + r];
            const float* xp = x1 + ((size_t)b * 2048 + j) * 128;
#pragma unroll
            for (int q = 0; q < 4; ++q) {
                float4 v = *(const float4*)(xp + t8 * 16 + q * 4);
                fr[t8 * 16 + q * 4 + 0] = v.x; fr[t8 * 16 + q * 4 + 1] = v.y;
                fr[t8 * 16 + q * 4 + 2] = v.z; fr[t8 * 16 + q * 4 + 3] = v.w;
            }
            if (t8 == 0) {
                const float* pj = pos1 + ((size_t)b * 2048 + j) * 3;
                fr[128] = pj[0] - cx; fr[129] = pj[1] - cy; fr[130] = pj[2] - cz;
                fr[131] = 0.f;
            }
        } else {
#pragma unroll
            for (int q = 0; q < 16; ++q) fr[t8 * 16 + q] = 0.f;
            if (t8 == 0) { fr[128] = 0.f; fr[129] = 0.f; fr[130] = 0.f; fr[131] = 0.f; }
        }
    }
    __syncthreads();

    const int r0 = (tid >> 5) * 4;
    const int c0 = (tid & 31) * 4;
    const int c8 = (tid & 31) * 8;

    {
        float acc[4][4];
#pragma unroll
        for (int i = 0; i < 4; ++i)
#pragma unroll
            for (int j = 0; j < 4; ++j) acc[i][j] = b1[c0 + j];
        for (int kb = 0; kb < 132; kb += 32) {
            const int kt = (132 - kb) < 32 ? (132 - kb) : 32;
            for (int l = tid; l < kt * 128; l += 512) {
                int k = l >> 7, cc = l & 127;
                sW[k * 128 + cc] = (kb + k < 131) ? w1[(size_t)(kb + k) * 128 + cc] : 0.f;
            }
            __syncthreads();
            tile44_fma(sF + r0 * 132 + kb, 132, sW + c0, 128, kt / 4, acc);
            __syncthreads();
        }
#pragma unroll
        for (int i = 0; i < 4; ++i)
#pragma unroll
            for (int j = 0; j < 4; ++j)
                sH[(r0 + i) * 132 + c0 + j] = fmaxf(acc[i][j], 0.f);
    }
    __syncthreads();

    {
        float acc[4][4];
#pragma unroll
        for (int i = 0; i < 4; ++i)
#pragma unroll
            for (int j = 0; j < 4; ++j) acc[i][j] = b2[c0 + j];
        for (int kb = 0; kb < 128; kb += 32) {
            for (int l = tid; l < 32 * 128; l += 512) {
                int k = l >> 7, cc = l & 127;
                sW[k * 128 + cc] = w2[(size_t)(kb + k) * 128 + cc];
            }
            __syncthreads();
            tile44_fma(sH + r0 * 132 + kb, 132, sW + c0, 128, 8, acc);
            __syncthreads();
        }
#pragma unroll
        for (int i = 0; i < 4; ++i)
#pragma unroll
            for (int j = 0; j < 4; ++j)
                sF[(r0 + i) * 132 + c0 + j] = fmaxf(acc[i][j], 0.f);
    }
    __syncthreads();

    {
        float acc[4][8];
#pragma unroll
        for (int i = 0; i < 4; ++i)
#pragma unroll
            for (int j = 0; j < 8; ++j) acc[i][j] = 0.f;
        for (int kb = 0; kb < 128; kb += 32) {
            for (int l = tid; l < 32 * 256; l += 512) {
                int k = l >> 8, cc = l & 255;
                sW[k * 256 + cc] = w3[(size_t)(kb + k) * 256 + cc];
            }
            __syncthreads();
            tile48_fma(sF + r0 * 132 + kb, 132, sW + c8, 256, 8, acc);
            __syncthreads();
        }
        float pm[8];
#pragma unroll
        for (int j = 0; j < 8; ++j) pm[j] = -__builtin_inff();
#pragma unroll
        for (int i = 0; i < 4; ++i)
            if (r0 + i < valid)
#pragma unroll
                for (int j = 0; j < 8; ++j) pm[j] = fmaxf(pm[j], acc[i][j]);
#pragma unroll
        for (int j = 0; j < 8; ++j) sRed[(tid >> 5) * 256 + c8 + j] = pm[j];
    }
    __syncthreads();
    if (tid < 256) {
        float m = -__builtin_inff();
#pragma unroll
        for (int g = 0; g < 16; ++g) m = fmaxf(m, sRed[g * 256 + tid]);
        x2[(size_t)c * 256 + tid] = m + b3[tid];
    }
}

// ---------------------------------------------------------------------------
// gemm1f: A = cat([x2, pos2]) built on the fly. K=259, relu.
// ---------------------------------------------------------------------------
__global__ __launch_bounds__(256) void gemm1f_kernel(const float* __restrict__ x2,
                                                     const float* __restrict__ pos2,
                                                     const float* __restrict__ W,
                                                     const float* __restrict__ bias,
                                                     float* __restrict__ C) {
    constexpr int K = 259, Nc = 256;
    __shared__ __align__(16) float sA[64 * 36];
    __shared__ __align__(16) float sB[32 * 68];
    const int tid = threadIdx.x;
    const int row0 = blockIdx.y * 64, col0 = blockIdx.x * 64;
    const int r0 = (tid >> 4) * 4, c0 = (tid & 15) * 4;
    float acc[4][4];
#pragma unroll
    for (int i = 0; i < 4; ++i)
#pragma unroll
        for (int j = 0; j < 4; ++j) acc[i][j] = 0.f;

    for (int kb = 0; kb < K; kb += 32) {
        for (int l = tid; l < 64 * 32; l += 256) {
            int r = l >> 5, k = l & 31;
            int gk = kb + k;
            float av = 0.f;
            if (gk < K) {
                int row = row0 + r;
                av = (gk < 256) ? x2[(size_t)row * 256 + gk]
                                : pos2[row * 3 + (gk - 256)];
            }
            sA[r * 36 + k] = av;
        }
        for (int l = tid; l < 32 * 64; l += 256) {
            int k = l >> 6, cc = l & 63;
            sB[k * 68 + cc] = (kb + k < K) ? W[(size_t)(kb + k) * Nc + col0 + cc] : 0.f;
        }
        __syncthreads();
        tile44_fma(sA + r0 * 36, 36, sB + c0, 68, 8, acc);
        __syncthreads();
    }
#pragma unroll
    for (int i = 0; i < 4; ++i)
#pragma unroll
        for (int j = 0; j < 4; ++j)
            C[(size_t)(row0 + r0 + i) * Nc + col0 + c0 + j] =
                fmaxf(acc[i][j] + bias[col0 + c0 + j], 0.f);
}

__global__ __launch_bounds__(256) void gemm_kernel(const float* __restrict__ A,
                                                   const float* __restrict__ W,
                                                   const float* __restrict__ bias,
                                                   float* __restrict__ C,
                                                   int M, int K, int Nc, int relu) {
    __shared__ __align__(16) float sA[64 * 36];
    __shared__ __align__(16) float sB[32 * 68];
    const int tid = threadIdx.x;
    const int row0 = blockIdx.y * 64, col0 = blockIdx.x * 64;
    const int r0 = (tid >> 4) * 4, c0 = (tid & 15) * 4;
    float acc[4][4];
#pragma unroll
    for (int i = 0; i < 4; ++i)
#pragma unroll
        for (int j = 0; j < 4; ++j) acc[i][j] = 0.f;

    for (int kb = 0; kb < K; kb += 32) {
        for (int l = tid; l < 64 * 32; l += 256) {
            int r = l >> 5, k = l & 31;
            sA[r * 36 + k] = (kb + k < K) ? A[(size_t)(row0 + r) * K + kb + k] : 0.f;
        }
        for (int l = tid; l < 32 * 64; l += 256) {
            int k = l >> 6, cc = l & 63;
            sB[k * 68 + cc] = (kb + k < K) ? W[(size_t)(kb + k) * Nc + col0 + cc] : 0.f;
        }
        __syncthreads();
        tile44_fma(sA + r0 * 36, 36, sB + c0, 68, 8, acc);
        __syncthreads();
    }
#pragma unroll
    for (int i = 0; i < 4; ++i)
#pragma unroll
        for (int j = 0; j < 4; ++j) {
            float v = acc[i][j] + bias[col0 + c0 + j];
            if (relu) v = fmaxf(v, 0.f);
            C[(size_t)(row0 + r0 + i) * Nc + col0 + c0 + j] = v;
        }
}

// ---------------------------------------------------------------------------
// maxpool over 512 rows + fc (1024->256), fused: one block per batch.
// ---------------------------------------------------------------------------
__global__ __launch_bounds__(1024) void mpfc_kernel(const float* __restrict__ h,
                                                    const float* __restrict__ w,
                                                    const float* __restrict__ bias,
                                                    float* __restrict__ out) {
    __shared__ float sG[1024];
    __shared__ float sP[4][256];
    const int b = blockIdx.x, tid = threadIdx.x;

    float m = -__builtin_inff();
    const float* hp = h + (size_t)b * 512 * 1024 + tid;
    for (int r = 0; r < 512; ++r) m = fmaxf(m, hp[(size_t)r * 1024]);
    sG[tid] = m;
    __syncthreads();

    const int c = tid & 255, kc = tid >> 8;
    float acc = 0.f;
    const float* wp = w + (size_t)(kc * 256) * 256 + c;
    const float* gp = sG + kc * 256;
    for (int k = 0; k < 256; ++k) acc = fmaf(gp[k], wp[(size_t)k * 256], acc);
    sP[kc][c] = acc;
    __syncthreads();
    if (tid < 256)
        out[b * 256 + tid] = ((sP[0][tid] + sP[1][tid]) + (sP[2][tid] + sP[3][tid]))
                             + bias[tid];
}

// ---------------------------------------------------------------------------
extern "C" void kernel_launch(void* const* d_in, const int* in_sizes, int n_in,
                              void* d_out, int out_size, void* d_ws, size_t ws_size,
                              hipStream_t stream) {
    const float* data  = (const float*)d_in[0];
    const float* s1w1  = (const float*)d_in[1];
    const float* s1b1  = (const float*)d_in[2];
    const float* s1w2  = (const float*)d_in[3];
    const float* s1b2  = (const float*)d_in[4];
    const float* s1w3  = (const float*)d_in[5];
    const float* s1b3  = (const float*)d_in[6];
    const float* s2w1  = (const float*)d_in[7];
    const float* s2b1  = (const float*)d_in[8];
    const float* s2w2  = (const float*)d_in[9];
    const float* s2b2  = (const float*)d_in[10];
    const float* s2w3  = (const float*)d_in[11];
    const float* s2b3  = (const float*)d_in[12];
    const float* s3w1  = (const float*)d_in[13];
    const float* s3b1  = (const float*)d_in[14];
    const float* s3w2  = (const float*)d_in[15];
    const float* s3b2  = (const float*)d_in[16];
    const float* s3w3  = (const float*)d_in[17];
    const float* s3b3  = (const float*)d_in[18];
    const float* fcw   = (const float*)d_in[19];
    const float* fcb   = (const float*)d_in[20];
    float* out = (float*)d_out;

    char* ws = (char*)d_ws;
    size_t o = 0;
    auto nxt = [&](size_t bytes) {
        size_t r = o;
        o += (bytes + 255) & ~(size_t)255;
        return r;
    };
    float* pos1 = (float*)(ws + nxt(4 * 2048 * 3 * 4));
    float* pos2 = (float*)(ws + nxt(4 * 512 * 3 * 4));
    float* mdG  = (float*)(ws + nxt(4 * 4096 * 4));
    int*   selG = (int*)(ws + nxt(4 * 2048 * 4));
    int*   nbr1 = (int*)(ws + nxt((size_t)8192 * 64 * 4));
    int*   cnt1 = (int*)(ws + nxt(8192 * 4));
    int*   nbr2 = (int*)(ws + nxt((size_t)2048 * 64 * 4));
    int*   cnt2 = (int*)(ws + nxt(2048 * 4));
    float* x1   = (float*)(ws + nxt((size_t)8192 * 128 * 4));
    float* x2   = (float*)(ws + nxt((size_t)2048 * 256 * 4));
    float* h1   = (float*)(ws + nxt((size_t)2048 * 256 * 4));
    float* h2   = (float*)(ws + nxt((size_t)2048 * 512 * 4));
    float* h3   = (float*)(ws + nxt((size_t)2048 * 1024 * 4));

    const float R1SQ = (float)(0.2 * 0.2);  // matches JAX weak-scalar f32 cast
    const float R2SQ = (float)(0.4 * 0.4);

    fps_chunk_kernel<<<4, 512, 0, stream>>>(data, mdG, selG, pos1, 1, 512);
    fps_chunk_kernel<<<4, 512, 0, stream>>>(data, mdG, selG, pos1, 512, 1024);
    fps_chunk_kernel<<<4, 512, 0, stream>>>(data, mdG, selG, pos1, 1024, 1536);
    fps_chunk_kernel<<<4, 512, 0, stream>>>(data, mdG, selG, pos1, 1536, 2048);
    nbr_kernel<4096, 1024><<<2048, 256, 0, stream>>>(data, pos1, 2048, R1SQ, nbr1, cnt1);
    mlp1s2_kernel<<<8196, 256, 0, stream>>>(data, pos1, nbr1, cnt1,
                                            s1w1, s1b1, s1w2, s1b2, s1w3, s1b3, x1,
                                            pos1, pos2);
    nbr_kernel<2048, 1536><<<512, 256, 0, stream>>>(pos1, pos2, 512, R2SQ, nbr2, cnt2);
    mlp2_kernel<<<2048, 512, 116736, stream>>>(x1, pos1, pos2, nbr2, cnt2,
                                               s2w1, s2b1, s2w2, s2b2, s2w3, s2b3, x2);
    gemm1f_kernel<<<dim3(4, 32), 256, 0, stream>>>(x2, pos2, s3w1, s3b1, h1);
    gemm_kernel<<<dim3(8, 32), 256, 0, stream>>>(h1, s3w2, s3b2, h2, 2048, 256, 512, 1);
    gemm_kernel<<<dim3(16, 32), 256, 0, stream>>>(h2, s3w3, s3b3, h3, 2048, 512, 1024, 0);
    mpfc_kernel<<<4, 1024, 0, stream>>>(h3, fcw, fcb, out);
}

// Round 8
// 2646.844 us; speedup vs baseline: 1.7130x; 1.2073x over previous
//
#include <hip/hip_runtime.h>

// ---------------------------------------------------------------------------
// PointNet++ (SSG) forward on MI355X.
// B=4, N=4096. sa1: S1=2048 r=0.2 K=64, MLP 6-64-64-128.
//              sa2: S2=512  r=0.4 K=64, MLP 131-128-128-256.
//              sa3: MLP 259-256-512-1024 + global max. fc: 1024->256.
// Discrete decisions (FPS argmax, radius membership, top-64 rank) are bitwise
// exact vs the f32 reference; __f*_rn blocks FMA contraction in d2.
// FPS argmax key = (f32bits<<32 | ~idx): non-negative f32 -> uint compare ==
// float compare; ~idx -> smaller-index-wins (jnp.argmax).
// r4: ext_vector v2f math regressed fps (scalarized) -- keep scalar form.
// r7: mlp2 showed 2 GB/dispatch phantom HBM traffic (scratch spill @128 VGPR
// + staged-weight LDS). r8: mlp2 reads weights direct-from-global (L2), LDS
// 116->67.6 KB (2 blocks/CU), 4 barriers instead of ~28. nbr1 quarters ride
// in the fps-chunk kernels' shadow; nbr2 rides in mlp1's kernel.
// ---------------------------------------------------------------------------

#define DEVFN __device__ __forceinline__

DEVFN float d2_exact(float ax, float ay, float az, float bx, float by, float bz) {
    float dx = __fsub_rn(ax, bx);
    float dy = __fsub_rn(ay, by);
    float dz = __fsub_rn(az, bz);
    return __fadd_rn(__fadd_rn(__fmul_rn(dx, dx), __fmul_rn(dy, dy)), __fmul_rn(dz, dz));
}

DEVFN unsigned long long u64max(unsigned long long a, unsigned long long b) {
    return a > b ? a : b;
}

template <int R>
DEVFN unsigned long long dpp_ror16_u64(unsigned long long x) {
    int lo = (int)(unsigned)(x & 0xFFFFFFFFull);
    int hi = (int)(unsigned)(x >> 32);
    lo = __builtin_amdgcn_update_dpp(lo, lo, 0x120 | R, 0xF, 0xF, false);
    hi = __builtin_amdgcn_update_dpp(hi, hi, 0x120 | R, 0xF, 0xF, false);
    return ((unsigned long long)(unsigned)hi << 32) | (unsigned)lo;
}

DEVFN unsigned long long rl_u64(unsigned long long x, int lane) {
    unsigned l = (unsigned)__builtin_amdgcn_readlane((int)(unsigned)(x & 0xFFFFFFFFull), lane);
    unsigned h = (unsigned)__builtin_amdgcn_readlane((int)(unsigned)(x >> 32), lane);
    return ((unsigned long long)h << 32) | l;
}

// ---------------------------------------------------------------------------
// FPS core (r3-validated u64-tree form), NT threads, one block.
// ---------------------------------------------------------------------------
template <int N, int S, int NT>
DEVFN void run_fps(const float* sx, const float* sy, const float* sz,
                   unsigned long long* sPack,  // [2][NT/64]
                   int* selLds) {
    constexpr int PPT = N / NT;
    constexpr int NW = NT / 64;
    const int tid = threadIdx.x;
    float px[PPT], py[PPT], pz[PPT], md[PPT];
    unsigned loc[PPT];
#pragma unroll
    for (int i = 0; i < PPT; ++i) {
        int idx = tid * PPT + i;
        px[i] = sx[idx]; py[i] = sy[idx]; pz[i] = sz[idx];
        md[i] = __builtin_inff();
        loc[i] = 0xFFFFFFFFu - (unsigned)idx;
    }
    if (tid == 0) selLds[0] = 0;
    int cur = 0;
    for (int s = 1; s < S; ++s) {
        float ax = sx[cur], ay = sy[cur], az = sz[cur];
        unsigned long long tq[PPT];
#pragma unroll
        for (int i = 0; i < PPT; ++i) {
            float d = d2_exact(px[i], py[i], pz[i], ax, ay, az);
            float m = fminf(md[i], d);
            md[i] = m;
            tq[i] = ((unsigned long long)__float_as_uint(m) << 32) |
                    (unsigned long long)loc[i];
        }
#pragma unroll
        for (int w = PPT / 2; w >= 1; w >>= 1)
#pragma unroll
            for (int i = 0; i < w; ++i) tq[i] = u64max(tq[i], tq[i + w]);

        unsigned long long pk = tq[0];
        pk = u64max(pk, dpp_ror16_u64<8>(pk));
        pk = u64max(pk, dpp_ror16_u64<4>(pk));
        pk = u64max(pk, dpp_ror16_u64<2>(pk));
        pk = u64max(pk, dpp_ror16_u64<1>(pk));

        unsigned long long wmax = u64max(u64max(rl_u64(pk, 0), rl_u64(pk, 16)),
                                         u64max(rl_u64(pk, 32), rl_u64(pk, 48)));

        unsigned long long* sp = sPack + (s & 1) * NW;
        if ((tid & 63) == 0) sp[tid >> 6] = wmax;
        __syncthreads();

        unsigned long long win;
        if constexpr (NW == 8) {
            const ulonglong2* sp2 = (const ulonglong2*)sp;
            ulonglong2 q0 = sp2[0], q1 = sp2[1], q2 = sp2[2], q3 = sp2[3];
            unsigned long long m01 = u64max(u64max(q0.x, q0.y), u64max(q1.x, q1.y));
            unsigned long long m23 = u64max(u64max(q2.x, q2.y), u64max(q3.x, q3.y));
            win = u64max(m01, m23);
        } else {
            const ulonglong2* sp2 = (const ulonglong2*)sp;
            ulonglong2 q0 = sp2[0], q1 = sp2[1];
            win = u64max(u64max(q0.x, q0.y), u64max(q1.x, q1.y));
        }

        cur = (int)(0xFFFFFFFFu - (unsigned)(win & 0xFFFFFFFFull));
        if (tid == 0) selLds[s] = cur;
    }
}

// ---------------------------------------------------------------------------
// Radius-neighbor body (r7-validated), one wave per center.
// ---------------------------------------------------------------------------
template <int N, int CAP>
DEVFN void nbr_body(const float* __restrict__ pos,   // batch base [N][3]
                    const float cx, const float cy, const float cz,
                    const float rsq, const int c,
                    int* __restrict__ nbr, int* __restrict__ cnt,
                    float* sDw, int* sIw) {
    const int lane = threadIdx.x & 63;
    int count = 0;
    for (int j = lane; j < N; j += 64) {
        float d = d2_exact(cx, cy, cz, pos[j * 3 + 0], pos[j * 3 + 1], pos[j * 3 + 2]);
        bool pred = (d <= rsq);
        unsigned long long m = __ballot(pred);
        int wpos = count + __popcll(m & ((1ull << lane) - 1ull));
        if (pred && wpos < CAP) { sDw[wpos] = d; sIw[wpos] = j; }
        count += __popcll(m);
    }
    if (count > CAP) count = CAP;

    for (int t = lane; t < count; t += 64) {
        float d = sDw[t]; int id = sIw[t];
        int rank = 0;
        int j0 = 0;
        for (; j0 + 4 <= count; j0 += 4) {
            float4 dj = *(const float4*)&sDw[j0];
            int4   ij = *(const int4*)&sIw[j0];
            rank += (dj.x < d || (dj.x == d && ij.x < id)) ? 1 : 0;
            rank += (dj.y < d || (dj.y == d && ij.y < id)) ? 1 : 0;
            rank += (dj.z < d || (dj.z == d && ij.z < id)) ? 1 : 0;
            rank += (dj.w < d || (dj.w == d && ij.w < id)) ? 1 : 0;
        }
        for (; j0 < count; ++j0) {
            float dj = sDw[j0]; int ij = sIw[j0];
            rank += (dj < d || (dj == d && ij < id)) ? 1 : 0;
        }
        if (rank < 64) nbr[(size_t)c * 64 + rank] = id;
    }
    if (lane == 0) cnt[c] = count < 64 ? count : 64;
}

// ---------------------------------------------------------------------------
// fpsnbr: blocks 0..3 = fps stage-1 chunk [sb,se); blocks 4.. = nbr1 for
// centers s in [s0, s0+512) of every batch (8 centers/block, 256 blocks).
// ---------------------------------------------------------------------------
__global__ __launch_bounds__(512) void fpsnbr_kernel(
    const float* __restrict__ data,   // [B][4096][3]
    float* __restrict__ mdG,          // [B][4096]
    int* __restrict__ selG,           // [B][2048]
    float* __restrict__ pos1,         // [B][2048][3]
    const int sb, const int se,
    const float rsq, int* __restrict__ nbr1, int* __restrict__ cnt1,
    const int s0)
{
    __shared__ __align__(16) char raw[65536];
    const int tid = threadIdx.x;

    if (blockIdx.x >= 4) {
        // ---- nbr1 for one quarter (needs pos1 rows [0, s0+512) = done) ----
        float* sD = (float*)raw;                 // [8][1024]
        int*   sI = (int*)(raw + 32768);         // [8][1024]
        const int wid = tid >> 6;
        const int g = (int)(blockIdx.x - 4) * 8 + wid;   // [0, 2048)
        const int b = g >> 9;
        const int s = s0 + (g & 511);
        const int c = b * 2048 + s;
        const float cx = pos1[(size_t)c * 3 + 0];
        const float cy = pos1[(size_t)c * 3 + 1];
        const float cz = pos1[(size_t)c * 3 + 2];
        nbr_body<4096, 1024>(data + (size_t)b * 4096 * 3, cx, cy, cz, rsq, c,
                             nbr1, cnt1, sD + wid * 1024, sI + wid * 1024);
        return;
    }

    // ---- fps stage-1 chunk (r7-validated) ----
    constexpr int N = 4096, NT = 512, PPT = N / NT, NW = NT / 64;
    float* sx = (float*)raw;
    float* sy = sx + 4096;
    float* sz = sy + 4096;
    unsigned long long* sPack = (unsigned long long*)(raw + 49152);  // [2][8]
    int* sSel = (int*)(raw + 49280);                                  // [512]

    const int b = blockIdx.x;
    const float* p = data + (size_t)b * N * 3;
    for (int i = tid; i < N; i += NT) {
        sx[i] = p[i * 3 + 0]; sy[i] = p[i * 3 + 1]; sz[i] = p[i * 3 + 2];
    }
    __syncthreads();

    float px[PPT], py[PPT], pz[PPT], md[PPT];
    const bool first = (sb == 1);
#pragma unroll
    for (int i = 0; i < PPT; ++i) {
        int idx = tid * PPT + i;
        px[i] = sx[idx]; py[i] = sy[idx]; pz[i] = sz[idx];
        md[i] = first ? __builtin_inff() : mdG[(size_t)b * N + idx];
    }
    int cur = first ? 0 : selG[(size_t)b * 2048 + sb - 1];
    if (first && tid == 0) selG[(size_t)b * 2048] = 0;
    const unsigned lob = 0xFFFFFFFFu - (unsigned)(tid * PPT);

    for (int s = sb; s < se; ++s) {
        float ax = sx[cur], ay = sy[cur], az = sz[cur];
        float mm[PPT];
#pragma unroll
        for (int i = 0; i < PPT; ++i) {
            float d = d2_exact(px[i], py[i], pz[i], ax, ay, az);
            float m = fminf(md[i], d);
            md[i] = m; mm[i] = m;
        }
        float a0 = fmaxf(mm[0], mm[4]), a1 = fmaxf(mm[1], mm[5]);
        float a2 = fmaxf(mm[2], mm[6]), a3 = fmaxf(mm[3], mm[7]);
        float b0 = fmaxf(a0, a2), b1 = fmaxf(a1, a3);
        float mloc = fmaxf(b0, b1);
        int li = 7;
#pragma unroll
        for (int i = 6; i >= 0; --i) li = (mm[i] == mloc) ? i : li;

        unsigned long long k0 =
            ((unsigned long long)__float_as_uint(mloc) << 32) |
            (unsigned long long)(lob - (unsigned)li);

        k0 = u64max(k0, dpp_ror16_u64<8>(k0));
        k0 = u64max(k0, dpp_ror16_u64<4>(k0));
        k0 = u64max(k0, dpp_ror16_u64<2>(k0));
        k0 = u64max(k0, dpp_ror16_u64<1>(k0));

        unsigned long long wmax = u64max(u64max(rl_u64(k0, 0), rl_u64(k0, 16)),
                                         u64max(rl_u64(k0, 32), rl_u64(k0, 48)));

        unsigned long long* sp = sPack + (s & 1) * NW;
        if ((tid & 63) == 0) sp[tid >> 6] = wmax;
        __syncthreads();

        const ulonglong2* sp2 = (const ulonglong2*)sp;
        ulonglong2 q0 = sp2[0], q1 = sp2[1], q2 = sp2[2], q3 = sp2[3];
        unsigned long long m01 = u64max(u64max(q0.x, q0.y), u64max(q1.x, q1.y));
        unsigned long long m23 = u64max(u64max(q2.x, q2.y), u64max(q3.x, q3.y));
        unsigned long long win = u64max(m01, m23);

        cur = (int)(0xFFFFFFFFu - (unsigned)(win & 0xFFFFFFFFull));
        if (tid == 0) sSel[s - sb] = cur;
    }
    __syncthreads();

    if (se < 2048) {
#pragma unroll
        for (int i = 0; i < PPT; ++i)
            mdG[(size_t)b * N + tid * PPT + i] = md[i];
    }
    if (tid == 0) selG[(size_t)b * 2048 + se - 1] = cur;

    float* p1 = pos1 + (size_t)b * 2048 * 3;
    const int sb0 = first ? 0 : sb;
    for (int s = sb0 + tid; s < se; s += NT) {
        int idx = (s == 0) ? 0 : sSel[s - sb];
        p1[s * 3 + 0] = sx[idx]; p1[s * 3 + 1] = sy[idx]; p1[s * 3 + 2] = sz[idx];
    }
}

// ---------------------------------------------------------------------------
// fps2nbr: blocks 0..3 = fps stage 2 (pos1 -> pos2); blocks 4.. = nbr1 Q4.
// ---------------------------------------------------------------------------
__global__ __launch_bounds__(512) void fps2nbr_kernel(
    const float* __restrict__ data,
    const float* __restrict__ pos1,   // [B][2048][3]
    float* __restrict__ pos2,         // [B][512][3]
    const float rsq, int* __restrict__ nbr1, int* __restrict__ cnt1,
    const int s0)
{
    __shared__ __align__(16) char raw[65536];
    const int tid = threadIdx.x;

    if (blockIdx.x >= 4) {
        float* sD = (float*)raw;
        int*   sI = (int*)(raw + 32768);
        const int wid = tid >> 6;
        const int g = (int)(blockIdx.x - 4) * 8 + wid;
        const int b = g >> 9;
        const int s = s0 + (g & 511);
        const int c = b * 2048 + s;
        const float cx = pos1[(size_t)c * 3 + 0];
        const float cy = pos1[(size_t)c * 3 + 1];
        const float cz = pos1[(size_t)c * 3 + 2];
        nbr_body<4096, 1024>(data + (size_t)b * 4096 * 3, cx, cy, cz, rsq, c,
                             nbr1, cnt1, sD + wid * 1024, sI + wid * 1024);
        return;
    }

    float* sx = (float*)raw;                              // [2048]
    float* sy = sx + 2048;
    float* sz = sy + 2048;
    int* sSel2 = (int*)(raw + 24576);                     // [512]
    unsigned long long* sPack2 = (unsigned long long*)(raw + 26624);  // [2][8]

    const int b = blockIdx.x;
    const float* p1 = pos1 + (size_t)b * 2048 * 3;
    for (int i = tid; i < 2048; i += 512) {
        sx[i] = p1[i * 3 + 0]; sy[i] = p1[i * 3 + 1]; sz[i] = p1[i * 3 + 2];
    }
    __syncthreads();

    run_fps<2048, 512, 512>(sx, sy, sz, sPack2, sSel2);
    __syncthreads();

    float* p2 = pos2 + (size_t)b * 512 * 3;
    {
        int si = sSel2[tid];
        p2[tid * 3 + 0] = sx[si]; p2[tid * 3 + 1] = sy[si]; p2[tid * 3 + 2] = sz[si];
    }
}

// ---------------------------------------------------------------------------
// Register-tile FMA helpers (A from LDS; W from LDS or global; float4 rows)
// ---------------------------------------------------------------------------
DEVFN void tile44_fma(const float* __restrict__ aBase, int aStride,
                      const float* __restrict__ wBase, int wStride,
                      int nk4, float (&acc)[4][4]) {
    for (int k4 = 0; k4 < nk4; ++k4) {
        float a[4][4], w[4][4];
#pragma unroll
        for (int i = 0; i < 4; ++i) {
            float4 t = *(const float4*)(aBase + i * aStride + k4 * 4);
            a[i][0] = t.x; a[i][1] = t.y; a[i][2] = t.z; a[i][3] = t.w;
        }
#pragma unroll
        for (int kk = 0; kk < 4; ++kk) {
            float4 t = *(const float4*)(wBase + (size_t)(k4 * 4 + kk) * wStride);
            w[kk][0] = t.x; w[kk][1] = t.y; w[kk][2] = t.z; w[kk][3] = t.w;
        }
#pragma unroll
        for (int kk = 0; kk < 4; ++kk)
#pragma unroll
            for (int i = 0; i < 4; ++i)
#pragma unroll
                for (int j = 0; j < 4; ++j)
                    acc[i][j] = fmaf(a[i][kk], w[kk][j], acc[i][j]);
    }
}

DEVFN void tile48_fma(const float* __restrict__ aBase, int aStride,
                      const float* __restrict__ wBase, int wStride,
                      int nk4, float (&acc)[4][8]) {
    for (int k4 = 0; k4 < nk4; ++k4) {
        float a[4][4];
#pragma unroll
        for (int i = 0; i < 4; ++i) {
            float4 t = *(const float4*)(aBase + i * aStride + k4 * 4);
            a[i][0] = t.x; a[i][1] = t.y; a[i][2] = t.z; a[i][3] = t.w;
        }
#pragma unroll
        for (int kk = 0; kk < 4; ++kk) {
            float4 t0 = *(const float4*)(wBase + (size_t)(k4 * 4 + kk) * wStride);
            float4 t1 = *(const float4*)(wBase + (size_t)(k4 * 4 + kk) * wStride + 4);
            float w_[8] = {t0.x, t0.y, t0.z, t0.w, t1.x, t1.y, t1.z, t1.w};
#pragma unroll
            for (int i = 0; i < 4; ++i)
#pragma unroll
                for (int j = 0; j < 8; ++j)
                    acc[i][j] = fmaf(a[i][kk], w_[j], acc[i][j]);
        }
    }
}

// ---------------------------------------------------------------------------
// mlp1nbr2: blocks 0..511 = nbr2 (pos2 centers over pos1 points);
// blocks 512.. = sa1 MLP per center (r6-validated body).
// ---------------------------------------------------------------------------
__global__ __launch_bounds__(256) void mlp1nbr2_kernel(
    const float* __restrict__ pos,   // [B][4096][3]
    const float* __restrict__ ctr,   // [8192][3] = pos1
    const int* __restrict__ nbr, const int* __restrict__ cnt,
    const float* __restrict__ w1, const float* __restrict__ b1,
    const float* __restrict__ w2, const float* __restrict__ b2,
    const float* __restrict__ w3, const float* __restrict__ b3,
    float* __restrict__ x1,          // [8192][128]
    const float* __restrict__ pos1,  // [B][2048][3]
    const float* __restrict__ pos2,  // [B][512][3]
    const float rsq2, int* __restrict__ nbr2, int* __restrict__ cnt2)
{
    __shared__ __align__(16) float smem[15424];
    const int tid = threadIdx.x;

    if (blockIdx.x < 512) {
        // ---- nbr2: 4 centers/block over [0,2048) ----
        float* sD = smem;                        // [4][1536]
        int*   sI = (int*)(smem + 6144);         // [4][1536]
        const int wid = tid >> 6;
        const int c = (int)blockIdx.x * 4 + wid;  // [0, 2048)
        const int b = c >> 9;
        const float cx = pos2[(size_t)c * 3 + 0];
        const float cy = pos2[(size_t)c * 3 + 1];
        const float cz = pos2[(size_t)c * 3 + 2];
        nbr_body<2048, 1536>(pos1 + (size_t)b * 2048 * 3, cx, cy, cz, rsq2, c,
                             nbr2, cnt2, sD + wid * 1536, sI + wid * 1536);
        return;
    }

    float* sFeat = smem;            // [64][9]
    float* sW    = smem + 576;      // w2 4096 ; layer3: w3 8192
    float* sH1   = smem + 4672;     // [64][68]
    float* sH2   = smem + 9024;     // [64][68]
    float* sRed  = smem + 13376;    // [16][128]

    const int c = blockIdx.x - 512;
    const int b = c >> 11;
    const int valid = cnt[c];

    if (tid < 64) {
        const int r = tid;
        float fx = 0.f, fy = 0.f, fz = 0.f, dx = 0.f, dy = 0.f, dz = 0.f;
        if (r < valid) {
            int j = nbr[(size_t)c * 64 + r];
            const float* pj = pos + ((size_t)b * 4096 + j) * 3;
            fx = pj[0]; fy = pj[1]; fz = pj[2];
            dx = fx - ctr[c * 3 + 0]; dy = fy - ctr[c * 3 + 1]; dz = fz - ctr[c * 3 + 2];
        }
        float* fr = sFeat + r * 9;
        fr[0] = fx; fr[1] = fy; fr[2] = fz; fr[3] = dx; fr[4] = dy; fr[5] = dz;
    }
    for (int l = tid; l < 4096; l += 256) sW[l] = w2[l];
    __syncthreads();

    {
        const int r = tid & 63, c0 = (tid >> 6) * 16;
        float acc[16];
#pragma unroll
        for (int q = 0; q < 16; ++q) acc[q] = b1[c0 + q];
#pragma unroll
        for (int k = 0; k < 6; ++k) {
            float a = sFeat[r * 9 + k];
#pragma unroll
            for (int q = 0; q < 16; ++q) acc[q] = fmaf(a, w1[k * 64 + c0 + q], acc[q]);
        }
        float* hr = sH1 + r * 68 + c0;
#pragma unroll
        for (int q = 0; q < 16; ++q) hr[q] = fmaxf(acc[q], 0.f);
    }
    __syncthreads();

    {
        const int r0 = (tid >> 4) * 4, c0 = (tid & 15) * 4;
        float acc[4][4];
#pragma unroll
        for (int i = 0; i < 4; ++i)
#pragma unroll
            for (int j = 0; j < 4; ++j) acc[i][j] = b2[c0 + j];
        tile44_fma(sH1 + r0 * 68, 68, sW + c0, 64, 16, acc);
#pragma unroll
        for (int i = 0; i < 4; ++i)
#pragma unroll
            for (int j = 0; j < 4; ++j)
                sH2[(r0 + i) * 68 + c0 + j] = fmaxf(acc[i][j], 0.f);
    }
    __syncthreads();

    for (int l = tid; l < 8192; l += 256) sW[l] = w3[l];
    __syncthreads();
    {
        const int r0 = (tid >> 4) * 4, c0 = (tid & 15) * 8;
        float acc[4][8];
#pragma unroll
        for (int i = 0; i < 4; ++i)
#pragma unroll
            for (int j = 0; j < 8; ++j) acc[i][j] = 0.f;
        tile48_fma(sH2 + r0 * 68, 68, sW + c0, 128, 16, acc);
        float pm[8];
#pragma unroll
        for (int j = 0; j < 8; ++j) pm[j] = -__builtin_inff();
#pragma unroll
        for (int i = 0; i < 4; ++i)
            if (r0 + i < valid)
#pragma unroll
                for (int j = 0; j < 8; ++j) pm[j] = fmaxf(pm[j], acc[i][j]);
#pragma unroll
        for (int j = 0; j < 8; ++j) sRed[(tid >> 4) * 128 + c0 + j] = pm[j];
    }
    __syncthreads();
    if (tid < 128) {
        float m = -__builtin_inff();
#pragma unroll
        for (int g = 0; g < 16; ++g) m = fmaxf(m, sRed[g * 128 + tid]);
        x1[(size_t)c * 128 + tid] = m + b3[tid];
    }
}

// ---------------------------------------------------------------------------
// sa2 MLP: one 64-row pass, 512 threads. Weights read DIRECT from global
// (L2-resident, coalesced float4 rows) -- no sW staging, 4 barriers total,
// LDS 67.6 KB -> 2 blocks/CU. FMA order identical to staged version.
// ---------------------------------------------------------------------------
__global__ __launch_bounds__(512, 4) void mlp2_kernel(
    const float* __restrict__ x1,    // [B*2048][128]
    const float* __restrict__ pos1,  // [B*2048][3]
    const float* __restrict__ ctr,   // [2048][3]
    const int* __restrict__ nbr, const int* __restrict__ cnt,
    const float* __restrict__ w1, const float* __restrict__ b1,
    const float* __restrict__ w2, const float* __restrict__ b2,
    const float* __restrict__ w3, const float* __restrict__ b3,
    float* __restrict__ x2)          // [2048][256]
{
    __shared__ __align__(16) float sF[64 * 132];   // feats, then h2
    __shared__ __align__(16) float sH[64 * 132];   // h1; sRed overlays after L2
    float* sRed = sH;                               // [16][256]

    const int tid = threadIdx.x;
    const int c = blockIdx.x;
    const int b = c >> 9;
    const int valid = cnt[c];
    const float cx = ctr[c * 3 + 0], cy = ctr[c * 3 + 1], cz = ctr[c * 3 + 2];

    {
        const int r = tid >> 3, t8 = tid & 7;
        float* fr = sF + r * 132;
        if (r < valid) {
            int j = nbr[(size_t)c * 64 + r];
            const float* xp = x1 + ((size_t)b * 2048 + j) * 128;
#pragma unroll
            for (int q = 0; q < 4; ++q) {
                float4 v = *(const float4*)(xp + t8 * 16 + q * 4);
                fr[t8 * 16 + q * 4 + 0] = v.x; fr[t8 * 16 + q * 4 + 1] = v.y;
                fr[t8 * 16 + q * 4 + 2] = v.z; fr[t8 * 16 + q * 4 + 3] = v.w;
            }
            if (t8 == 0) {
                const float* pj = pos1 + ((size_t)b * 2048 + j) * 3;
                fr[128] = pj[0] - cx; fr[129] = pj[1] - cy; fr[130] = pj[2] - cz;
                fr[131] = 0.f;
            }
        } else {
#pragma unroll
            for (int q = 0; q < 16; ++q) fr[t8 * 16 + q] = 0.f;
            if (t8 == 0) { fr[128] = 0.f; fr[129] = 0.f; fr[130] = 0.f; fr[131] = 0.f; }
        }
    }
    __syncthreads();

    const int r0 = (tid >> 5) * 4;        // 16 row-groups x 4 rows
    const int c0 = (tid & 31) * 4;        // l1/l2 cols
    const int c8 = (tid & 31) * 8;        // l3 cols

    // layer1: K=131 (128 via tiles + 3 tail), w1 direct from global
    {
        float acc[4][4];
#pragma unroll
        for (int i = 0; i < 4; ++i)
#pragma unroll
            for (int j = 0; j < 4; ++j) acc[i][j] = b1[c0 + j];
        tile44_fma(sF + r0 * 132, 132, w1 + c0, 128, 32, acc);
        for (int k = 128; k < 131; ++k) {
            float4 wv = *(const float4*)(w1 + (size_t)k * 128 + c0);
            float w_[4] = {wv.x, wv.y, wv.z, wv.w};
#pragma unroll
            for (int i = 0; i < 4; ++i) {
                float a = sF[(r0 + i) * 132 + k];
#pragma unroll
                for (int j = 0; j < 4; ++j) acc[i][j] = fmaf(a, w_[j], acc[i][j]);
            }
        }
#pragma unroll
        for (int i = 0; i < 4; ++i)
#pragma unroll
            for (int j = 0; j < 4; ++j)
                sH[(r0 + i) * 132 + c0 + j] = fmaxf(acc[i][j], 0.f);
    }
    __syncthreads();

    // layer2: K=128, sH -> sF (h2), w2 direct
    {
        float acc[4][4];
#pragma unroll
        for (int i = 0; i < 4; ++i)
#pragma unroll
            for (int j = 0; j < 4; ++j) acc[i][j] = b2[c0 + j];
        tile44_fma(sH + r0 * 132, 132, w2 + c0, 128, 32, acc);
#pragma unroll
        for (int i = 0; i < 4; ++i)
#pragma unroll
            for (int j = 0; j < 4; ++j)
                sF[(r0 + i) * 132 + c0 + j] = fmaxf(acc[i][j], 0.f);
    }
    __syncthreads();

    // layer3: K=128, cols=256, w3 direct; masked col-max
    {
        float acc[4][8];
#pragma unroll
        for (int i = 0; i < 4; ++i)
#pragma unroll
            for (int j = 0; j < 8; ++j) acc[i][j] = 0.f;
        tile48_fma(sF + r0 * 132, 132, w3 + c8, 256, 32, acc);
        float pm[8];
#pragma unroll
        for (int j = 0; j < 8; ++j) pm[j] = -__builtin_inff();
#pragma unroll
        for (int i = 0; i < 4; ++i)
            if (r0 + i < valid)
#pragma unroll
                for (int j = 0; j < 8; ++j) pm[j] = fmaxf(pm[j], acc[i][j]);
#pragma unroll
        for (int j = 0; j < 8; ++j) sRed[(tid >> 5) * 256 + c8 + j] = pm[j];
    }
    __syncthreads();
    if (tid < 256) {
        float m = -__builtin_inff();
#pragma unroll
        for (int g = 0; g < 16; ++g) m = fmaxf(m, sRed[g * 256 + tid]);
        x2[(size_t)c * 256 + tid] = m + b3[tid];
    }
}

// ---------------------------------------------------------------------------
// gemm1f: A = cat([x2, pos2]) on the fly. K=259, relu.
// ---------------------------------------------------------------------------
__global__ __launch_bounds__(256) void gemm1f_kernel(const float* __restrict__ x2,
                                                     const float* __restrict__ pos2,
                                                     const float* __restrict__ W,
                                                     const float* __restrict__ bias,
                                                     float* __restrict__ C) {
    constexpr int K = 259, Nc = 256;
    __shared__ __align__(16) float sA[64 * 36];
    __shared__ __align__(16) float sB[32 * 68];
    const int tid = threadIdx.x;
    const int row0 = blockIdx.y * 64, col0 = blockIdx.x * 64;
    const int r0 = (tid >> 4) * 4, c0 = (tid & 15) * 4;
    float acc[4][4];
#pragma unroll
    for (int i = 0; i < 4; ++i)
#pragma unroll
        for (int j = 0; j < 4; ++j) acc[i][j] = 0.f;

    for (int kb = 0; kb < K; kb += 32) {
        for (int l = tid; l < 64 * 32; l += 256) {
            int r = l >> 5, k = l & 31;
            int gk = kb + k;
            float av = 0.f;
            if (gk < K) {
                int row = row0 + r;
                av = (gk < 256) ? x2[(size_t)row * 256 + gk]
                                : pos2[row * 3 + (gk - 256)];
            }
            sA[r * 36 + k] = av;
        }
        for (int l = tid; l < 32 * 64; l += 256) {
            int k = l >> 6, cc = l & 63;
            sB[k * 68 + cc] = (kb + k < K) ? W[(size_t)(kb + k) * Nc + col0 + cc] : 0.f;
        }
        __syncthreads();
        tile44_fma(sA + r0 * 36, 36, sB + c0, 68, 8, acc);
        __syncthreads();
    }
#pragma unroll
    for (int i = 0; i < 4; ++i)
#pragma unroll
        for (int j = 0; j < 4; ++j)
            C[(size_t)(row0 + r0 + i) * Nc + col0 + c0 + j] =
                fmaxf(acc[i][j] + bias[col0 + c0 + j], 0.f);
}

__global__ __launch_bounds__(256) void gemm_kernel(const float* __restrict__ A,
                                                   const float* __restrict__ W,
                                                   const float* __restrict__ bias,
                                                   float* __restrict__ C,
                                                   int M, int K, int Nc, int relu) {
    __shared__ __align__(16) float sA[64 * 36];
    __shared__ __align__(16) float sB[32 * 68];
    const int tid = threadIdx.x;
    const int row0 = blockIdx.y * 64, col0 = blockIdx.x * 64;
    const int r0 = (tid >> 4) * 4, c0 = (tid & 15) * 4;
    float acc[4][4];
#pragma unroll
    for (int i = 0; i < 4; ++i)
#pragma unroll
        for (int j = 0; j < 4; ++j) acc[i][j] = 0.f;

    for (int kb = 0; kb < K; kb += 32) {
        for (int l = tid; l < 64 * 32; l += 256) {
            int r = l >> 5, k = l & 31;
            sA[r * 36 + k] = (kb + k < K) ? A[(size_t)(row0 + r) * K + kb + k] : 0.f;
        }
        for (int l = tid; l < 32 * 64; l += 256) {
            int k = l >> 6, cc = l & 63;
            sB[k * 68 + cc] = (kb + k < K) ? W[(size_t)(kb + k) * Nc + col0 + cc] : 0.f;
        }
        __syncthreads();
        tile44_fma(sA + r0 * 36, 36, sB + c0, 68, 8, acc);
        __syncthreads();
    }
#pragma unroll
    for (int i = 0; i < 4; ++i)
#pragma unroll
        for (int j = 0; j < 4; ++j) {
            float v = acc[i][j] + bias[col0 + c0 + j];
            if (relu) v = fmaxf(v, 0.f);
            C[(size_t)(row0 + r0 + i) * Nc + col0 + c0 + j] = v;
        }
}

// ---------------------------------------------------------------------------
// maxpool over 512 rows + fc (1024->256), fused: one block per batch.
// ---------------------------------------------------------------------------
__global__ __launch_bounds__(1024) void mpfc_kernel(const float* __restrict__ h,
                                                    const float* __restrict__ w,
                                                    const float* __restrict__ bias,
                                                    float* __restrict__ out) {
    __shared__ float sG[1024];
    __shared__ float sP[4][256];
    const int b = blockIdx.x, tid = threadIdx.x;

    float m = -__builtin_inff();
    const float* hp = h + (size_t)b * 512 * 1024 + tid;
    for (int r = 0; r < 512; ++r) m = fmaxf(m, hp[(size_t)r * 1024]);
    sG[tid] = m;
    __syncthreads();

    const int c = tid & 255, kc = tid >> 8;
    float acc = 0.f;
    const float* wp = w + (size_t)(kc * 256) * 256 + c;
    const float* gp = sG + kc * 256;
    for (int k = 0; k < 256; ++k) acc = fmaf(gp[k], wp[(size_t)k * 256], acc);
    sP[kc][c] = acc;
    __syncthreads();
    if (tid < 256)
        out[b * 256 + tid] = ((sP[0][tid] + sP[1][tid]) + (sP[2][tid] + sP[3][tid]))
                             + bias[tid];
}

// ---------------------------------------------------------------------------
extern "C" void kernel_launch(void* const* d_in, const int* in_sizes, int n_in,
                              void* d_out, int out_size, void* d_ws, size_t ws_size,
                              hipStream_t stream) {
    const float* data  = (const float*)d_in[0];
    const float* s1w1  = (const float*)d_in[1];
    const float* s1b1  = (const float*)d_in[2];
    const float* s1w2  = (const float*)d_in[3];
    const float* s1b2  = (const float*)d_in[4];
    const float* s1w3  = (const float*)d_in[5];
    const float* s1b3  = (const float*)d_in[6];
    const float* s2w1  = (const float*)d_in[7];
    const float* s2b1  = (const float*)d_in[8];
    const float* s2w2  = (const float*)d_in[9];
    const float* s2b2  = (const float*)d_in[10];
    const float* s2w3  = (const float*)d_in[11];
    const float* s2b3  = (const float*)d_in[12];
    const float* s3w1  = (const float*)d_in[13];
    const float* s3b1  = (const float*)d_in[14];
    const float* s3w2  = (const float*)d_in[15];
    const float* s3b2  = (const float*)d_in[16];
    const float* s3w3  = (const float*)d_in[17];
    const float* s3b3  = (const float*)d_in[18];
    const float* fcw   = (const float*)d_in[19];
    const float* fcb   = (const float*)d_in[20];
    float* out = (float*)d_out;

    char* ws = (char*)d_ws;
    size_t o = 0;
    auto nxt = [&](size_t bytes) {
        size_t r = o;
        o += (bytes + 255) & ~(size_t)255;
        return r;
    };
    float* pos1 = (float*)(ws + nxt(4 * 2048 * 3 * 4));
    float* pos2 = (float*)(ws + nxt(4 * 512 * 3 * 4));
    float* mdG  = (float*)(ws + nxt(4 * 4096 * 4));
    int*   selG = (int*)(ws + nxt(4 * 2048 * 4));
    int*   nbr1 = (int*)(ws + nxt((size_t)8192 * 64 * 4));
    int*   cnt1 = (int*)(ws + nxt(8192 * 4));
    int*   nbr2 = (int*)(ws + nxt((size_t)2048 * 64 * 4));
    int*   cnt2 = (int*)(ws + nxt(2048 * 4));
    float* x1   = (float*)(ws + nxt((size_t)8192 * 128 * 4));
    float* x2   = (float*)(ws + nxt((size_t)2048 * 256 * 4));
    float* h1   = (float*)(ws + nxt((size_t)2048 * 256 * 4));
    float* h2   = (float*)(ws + nxt((size_t)2048 * 512 * 4));
    float* h3   = (float*)(ws + nxt((size_t)2048 * 1024 * 4));

    const float R1SQ = (float)(0.2 * 0.2);  // matches JAX weak-scalar f32 cast
    const float R2SQ = (float)(0.4 * 0.4);

    // fps chunks with nbr1 quarters riding in the shadow (260 blocks: 4 fps
    // + 256 nbr of 8 centers each). nbr quarter q needs pos1 rows < 512(q+1),
    // written by the previous chunk kernel.
    fpsnbr_kernel<<<4, 512, 0, stream>>>(data, mdG, selG, pos1, 1, 512,
                                         R1SQ, nbr1, cnt1, 0);
    fpsnbr_kernel<<<260, 512, 0, stream>>>(data, mdG, selG, pos1, 512, 1024,
                                           R1SQ, nbr1, cnt1, 0);
    fpsnbr_kernel<<<260, 512, 0, stream>>>(data, mdG, selG, pos1, 1024, 1536,
                                           R1SQ, nbr1, cnt1, 512);
    fpsnbr_kernel<<<260, 512, 0, stream>>>(data, mdG, selG, pos1, 1536, 2048,
                                           R1SQ, nbr1, cnt1, 1024);
    fps2nbr_kernel<<<260, 512, 0, stream>>>(data, pos1, pos2,
                                            R1SQ, nbr1, cnt1, 1536);
    mlp1nbr2_kernel<<<512 + 8192, 256, 0, stream>>>(data, pos1, nbr1, cnt1,
                                                    s1w1, s1b1, s1w2, s1b2,
                                                    s1w3, s1b3, x1,
                                                    pos1, pos2, R2SQ, nbr2, cnt2);
    mlp2_kernel<<<2048, 512, 0, stream>>>(x1, pos1, pos2, nbr2, cnt2,
                                          s2w1, s2b1, s2w2, s2b2, s2w3, s2b3, x2);
    gemm1f_kernel<<<dim3(4, 32), 256, 0, stream>>>(x2, pos2, s3w1, s3b1, h1);
    gemm_kernel<<<dim3(8, 32), 256, 0, stream>>>(h1, s3w2, s3b2, h2, 2048, 256, 512, 1);
    gemm_kernel<<<dim3(16, 32), 256, 0, stream>>>(h2, s3w3, s3b3, h3, 2048, 512, 1024, 0);
    mpfc_kernel<<<4, 1024, 0, stream>>>(h3, fcw, fcb, out);
}